// Round 5
// baseline (620.015 us; speedup 1.0000x reference)
//
#include <hip/hip_runtime.h>
#include <math.h>

// ============================================================================
// ViT block on MI355X — Round 8:
//   * GEMM/patch kernels: NO LDS. MFMA fragments loaded global->register
//     directly (16B/lane, per-lane row addressing). Zero barriers, zero
//     waitcnt drains — at K=256/1024 the LDS staging+barrier machinery was
//     the bottleneck (MfmaUtil 11.6%, HBM 22%, nothing saturated).
//   * MFMA operands swapped: acc holds 4 consecutive N-elems per quad ->
//     epilogue uses 8B/16B vector stores + float4 bias/res loads
//     (was 64 scalar 2B stores).
//   * Attention, LN+PE, cvt, workspace unchanged.
// ============================================================================

#define M_TOK 32768

typedef __attribute__((ext_vector_type(8))) short  short8;   // 8 bf16 (4 VGPRs)
typedef __attribute__((ext_vector_type(4))) float  f32x4;
typedef __attribute__((ext_vector_type(8))) unsigned short us8v;
typedef __attribute__((ext_vector_type(4))) unsigned short us4v;

__device__ __forceinline__ unsigned short f2b(float f) {
    union { float f; unsigned u; } c; c.f = f;
    unsigned r = c.u + 0x7fffu + ((c.u >> 16) & 1u);   // RNE
    return (unsigned short)(r >> 16);
}
__device__ __forceinline__ float gelu_fast(float x) {
    // 0.5x(1+tanh(c0(x+0.044715x^3))) == x * sigmoid(2*c0*(x+0.044715x^3))
    const float c0 = 0.7978845608028654f;            // sqrt(2/pi)
    const float c1 = 0.044715f * 0.7978845608028654f;
    float z = x * (c0 + c1 * x * x);
    float e = __expf(-2.0f * z);
    return x * __builtin_amdgcn_rcpf(1.0f + e);
}

// ---------------------------------------------------------------------------
// fp32 -> bf16 convert (n % 4 == 0) — used for the big image tensor only
// ---------------------------------------------------------------------------
__global__ __launch_bounds__(256) void cvt_f2b_kernel(
    const float* __restrict__ in, unsigned short* __restrict__ out, int n)
{
    int i = (blockIdx.x * 256 + threadIdx.x) * 4;
    if (i >= n) return;
    float4 v = *(const float4*)(in + i);
    us4v o;
    o[0] = f2b(v.x); o[1] = f2b(v.y); o[2] = f2b(v.z); o[3] = f2b(v.w);
    *(us4v*)(out + i) = o;
}

// ---------------------------------------------------------------------------
// All 5 weight tensors converted in ONE launch (ranges in 1024-elem blocks):
//   conv_w 196608 -> 192 | qkv_w 196608 -> 192 | proj_w 65536 -> 64
//   ff_w1 262144 -> 256  | ff_w2 262144 -> 256   (total 960 blocks)
// ---------------------------------------------------------------------------
__global__ __launch_bounds__(256) void cvt_weights_kernel(
    const float* __restrict__ s0, const float* __restrict__ s1,
    const float* __restrict__ s2, const float* __restrict__ s3,
    const float* __restrict__ s4,
    unsigned short* __restrict__ d0, unsigned short* __restrict__ d1,
    unsigned short* __restrict__ d2, unsigned short* __restrict__ d3,
    unsigned short* __restrict__ d4)
{
    const int bid = blockIdx.x;
    const float* src; unsigned short* dst; int off;
    if      (bid < 192) { src = s0; dst = d0; off = bid; }
    else if (bid < 384) { src = s1; dst = d1; off = bid - 192; }
    else if (bid < 448) { src = s2; dst = d2; off = bid - 384; }
    else if (bid < 704) { src = s3; dst = d3; off = bid - 448; }
    else                { src = s4; dst = d4; off = bid - 704; }
    const int i = off * 1024 + threadIdx.x * 4;
    float4 v = *(const float4*)(src + i);
    us4v o;
    o[0] = f2b(v.x); o[1] = f2b(v.y); o[2] = f2b(v.z); o[3] = f2b(v.w);
    *(us4v*)(dst + i) = o;
}

// ---------------------------------------------------------------------------
// Sinusoidal PE table: pe[pos][d], pos<1024, d<256.
// ---------------------------------------------------------------------------
__global__ __launch_bounds__(256) void pe_init_kernel(float* __restrict__ pe)
{
    const int pos = blockIdx.x;
    const int d   = threadIdx.x;
    const int ieven = d & ~1;
    float div = expf(-9.210340371976184f * (float)ieven * (1.0f / 256.0f));
    float ang = (float)pos * div;
    pe[pos * 256 + d] = (d & 1) ? cosf(ang) : sinf(ang);
}

// ---------------------------------------------------------------------------
// Direct-register MFMA GEMM: C = A (MxK) . W^T (NxK) + bias (+gelu/res)
// 128x128 tile, 256 thr = 4 waves 2x2, NO LDS, NO barriers.
// Fragments: lane reads A[m0+wr+i*16+l15][kc*32+quad*8 +0..7] (16B) and
//            W[n0+wc+j*16+l15][same] directly.
// MFMA operands SWAPPED (wf first): D row-dim = N, col-dim = M, so thread
// (l15,quad) holds m = l15 (fixed), n = quad*4+r (4 consecutive) -> 8B/16B
// vector epilogue stores. Sum order over K identical to prior rounds.
// ---------------------------------------------------------------------------
template<bool GELU, bool RES, bool WF32, bool WB16>
__global__ __launch_bounds__(256) void mfma_gemm_kernel(
    const unsigned short* __restrict__ A, const unsigned short* __restrict__ W,
    const float* __restrict__ bias, const float* __restrict__ res,
    float* __restrict__ outF, unsigned short* __restrict__ outB,
    int M, int N, int K)
{
    const int t    = threadIdx.x;
    const int m0   = blockIdx.x * 128;
    const int n0   = blockIdx.y * 128;
    const int wv   = t >> 6, lane = t & 63;
    const int wr   = (wv >> 1) * 64, wc = (wv & 1) * 64;
    const int l15  = lane & 15, quad = lane >> 4;

    f32x4 acc[4][4];   // [j (N-sub)][i (M-sub)]
#pragma unroll
    for (int j = 0; j < 4; j++)
#pragma unroll
        for (int i = 0; i < 4; i++)
#pragma unroll
            for (int r = 0; r < 4; r++) acc[j][i][r] = 0.0f;

    const unsigned short* pA[4];
    const unsigned short* pW[4];
#pragma unroll
    for (int i = 0; i < 4; i++)
        pA[i] = A + (size_t)(m0 + wr + i * 16 + l15) * K + quad * 8;
#pragma unroll
    for (int j = 0; j < 4; j++)
        pW[j] = W + (size_t)(n0 + wc + j * 16 + l15) * K + quad * 8;

#define LOADF(AF, WF, kc)                                                      \
    {                                                                          \
        _Pragma("unroll")                                                      \
        for (int i = 0; i < 4; i++) AF[i] = *(const short8*)(pA[i] + (kc) * 32); \
        _Pragma("unroll")                                                      \
        for (int j = 0; j < 4; j++) WF[j] = *(const short8*)(pW[j] + (kc) * 32); \
    }
#define MF(AF, WF)                                                             \
    {                                                                          \
        _Pragma("unroll")                                                      \
        for (int j = 0; j < 4; j++)                                            \
            _Pragma("unroll")                                                  \
            for (int i = 0; i < 4; i++)                                        \
                acc[j][i] = __builtin_amdgcn_mfma_f32_16x16x32_bf16(           \
                    WF[j], AF[i], acc[j][i], 0, 0, 0);                         \
    }

    const int ks = K >> 5;                 // 8 or 24 or 32 (always even)
    short8 a0[4], w0[4], a1[4], w1[4];
    LOADF(a0, w0, 0);
    for (int kc = 0; kc < ks; kc += 2) {
        LOADF(a1, w1, kc + 1);
        MF(a0, w0);
        if (kc + 2 < ks) LOADF(a0, w0, kc + 2);
        MF(a1, w1);
    }
#undef LOADF
#undef MF

    // Epilogue: thread owns rows m = l15-based, cols nb..nb+3 (consecutive).
#pragma unroll
    for (int j = 0; j < 4; j++) {
        const int nb = n0 + wc + j * 16 + quad * 4;
        const f32x4 bv = *(const f32x4*)(bias + nb);
#pragma unroll
        for (int i = 0; i < 4; i++) {
            const size_t row = (size_t)(m0 + wr + i * 16 + l15) * N + nb;
            f32x4 v;
#pragma unroll
            for (int r = 0; r < 4; r++) {
                float x = acc[j][i][r] + bv[r];
                if (GELU) x = gelu_fast(x);
                v[r] = x;
            }
            if (RES) {
                const f32x4 rr = *(const f32x4*)(res + row);
#pragma unroll
                for (int r = 0; r < 4; r++) v[r] += rr[r];
            }
            if (WF32) *(f32x4*)(outF + row) = v;
            if (WB16) {
                us4v o;
#pragma unroll
                for (int r = 0; r < 4; r++) o[r] = f2b(v[r]);
                *(us4v*)(outB + row) = o;
            }
        }
    }
}

// ---------------------------------------------------------------------------
// Direct-register patch-embed GEMM: A gathered from bf16 image xb.
// Same no-LDS structure; per-lane A address = patch gather (16B contiguous
// within one pixel row: k-chunk = 8 px, pw in {0,8}). K=768, ks=24.
// ---------------------------------------------------------------------------
__global__ __launch_bounds__(256) void patch_mfma_kernel(
    const unsigned short* __restrict__ xb, const unsigned short* __restrict__ W,
    const float* __restrict__ bias, float* __restrict__ outF)
{
    const int t    = threadIdx.x;
    const int m0   = blockIdx.x * 128;
    const int n0   = blockIdx.y * 128;
    const int wv   = t >> 6, lane = t & 63;
    const int wr   = (wv >> 1) * 64, wc = (wv & 1) * 64;
    const int l15  = lane & 15, quad = lane >> 4;

    f32x4 acc[4][4];
#pragma unroll
    for (int j = 0; j < 4; j++)
#pragma unroll
        for (int i = 0; i < 4; i++)
#pragma unroll
            for (int r = 0; r < 4; r++) acc[j][i][r] = 0.0f;

    size_t xoffP[4];
#pragma unroll
    for (int i = 0; i < 4; i++) {
        const int m   = m0 + wr + i * 16 + l15;
        const int b   = m >> 10;
        const int idx = m & 1023;
        const int hh  = idx >> 5, ww = idx & 31;
        xoffP[i] = (size_t)b * 786432 + (size_t)hh * 8192 + ww * 16;
    }
    const unsigned short* pW[4];
#pragma unroll
    for (int j = 0; j < 4; j++)
        pW[j] = W + (size_t)(n0 + wc + j * 16 + l15) * 768 + quad * 8;

#define PLOADF(AF, WF, kc)                                                     \
    {                                                                          \
        const int k  = (kc) * 32 + quad * 8;                                   \
        const int c  = k >> 8;                                                 \
        const int ph = (k >> 4) & 15;                                          \
        const int pw = k & 15;                                                 \
        const size_t koff = (size_t)c * 262144 + (size_t)ph * 512 + pw;        \
        _Pragma("unroll")                                                      \
        for (int i = 0; i < 4; i++) AF[i] = *(const short8*)(xb + xoffP[i] + koff); \
        _Pragma("unroll")                                                      \
        for (int j = 0; j < 4; j++) WF[j] = *(const short8*)(pW[j] + (kc) * 32); \
    }
#define PMF(AF, WF)                                                            \
    {                                                                          \
        _Pragma("unroll")                                                      \
        for (int j = 0; j < 4; j++)                                            \
            _Pragma("unroll")                                                  \
            for (int i = 0; i < 4; i++)                                        \
                acc[j][i] = __builtin_amdgcn_mfma_f32_16x16x32_bf16(           \
                    WF[j], AF[i], acc[j][i], 0, 0, 0);                         \
    }

    short8 a0[4], w0[4], a1[4], w1[4];
    PLOADF(a0, w0, 0);
    for (int kc = 0; kc < 24; kc += 2) {
        PLOADF(a1, w1, kc + 1);
        PMF(a0, w0);
        if (kc + 2 < 24) PLOADF(a0, w0, kc + 2);
        PMF(a1, w1);
    }
#undef PLOADF
#undef PMF

#pragma unroll
    for (int j = 0; j < 4; j++) {
        const int nb = n0 + wc + j * 16 + quad * 4;
        const f32x4 bv = *(const f32x4*)(bias + nb);
#pragma unroll
        for (int i = 0; i < 4; i++) {
            const size_t row = (size_t)(m0 + wr + i * 16 + l15) * 256 + nb;
            f32x4 v;
#pragma unroll
            for (int r = 0; r < 4; r++) v[r] = acc[j][i][r] + bv[r];
            *(f32x4*)(outF + row) = v;
        }
    }
}

// ---------------------------------------------------------------------------
// LayerNorm + PE (table lookup). One block = one token (256 features).
// ---------------------------------------------------------------------------
__global__ __launch_bounds__(256) void ln_pe_kernel(
    const float* __restrict__ in, const float* __restrict__ w,
    const float* __restrict__ b, const float* __restrict__ pe_t,
    float* __restrict__ outF, unsigned short* __restrict__ outB)
{
    const int m = blockIdx.x;
    const int d = threadIdx.x;
    float v = in[(size_t)m * 256 + d];

    float s = v, s2 = v * v;
#pragma unroll
    for (int off = 32; off > 0; off >>= 1) {
        s  += __shfl_down(s,  off, 64);
        s2 += __shfl_down(s2, off, 64);
    }
    __shared__ float ss[4], ss2[4], stats[2];
    const int lane = d & 63, wid = d >> 6;
    if (lane == 0) { ss[wid] = s; ss2[wid] = s2; }
    __syncthreads();
    if (d == 0) {
        float a  = ss[0] + ss[1] + ss[2] + ss[3];
        float a2 = ss2[0] + ss2[1] + ss2[2] + ss2[3];
        float mean = a * (1.0f / 256.0f);
        float var  = a2 * (1.0f / 256.0f) - mean * mean;
        stats[0] = mean;
        stats[1] = rsqrtf(var + 1e-5f);
    }
    __syncthreads();
    const float mean = stats[0], rstd = stats[1];

    const int pos = m & 1023;
    float pe = pe_t[pos * 256 + d];

    float o = (v - mean) * rstd * w[d] + b[d] + pe;
    outF[(size_t)m * 256 + d] = o;
    outB[(size_t)m * 256 + d] = f2b(o);
}

// ---------------------------------------------------------------------------
// MFMA windowed attention. One block = one (batch, window, head).
// ---------------------------------------------------------------------------
__global__ __launch_bounds__(256) void attn_mfma_kernel(
    const unsigned short* __restrict__ qkv, unsigned short* __restrict__ out)
{
    __shared__ unsigned short Ps[64 * 72];   // P, stride 72 (b128-aligned, padded)
    __shared__ unsigned short Vt[32 * 72];   // V^T [headdim][key]

    const int blk = blockIdx.x;        // 0..4095
    const int h = blk & 7;
    const int w = (blk >> 3) & 15;
    const int b = blk >> 7;
    const int m_base = b * 1024 + w * 64;

    const int t = threadIdx.x;
    const int wv = t >> 6, lane = t & 63;
    const int l15 = lane & 15, quad = lane >> 4;

    // ---- stage V^T (cooperative, 8 elems/thread) ----
    {
        const int row = t >> 2;             // key 0..63
        const int c0  = (t & 3) * 8;        // headdim chunk
        const unsigned short* src = qkv + (size_t)(m_base + row) * 768 + 512 + h * 32 + c0;
        us8v v = *(const us8v*)src;
#pragma unroll
        for (int j = 0; j < 8; j++) Vt[(c0 + j) * 72 + row] = v[j];
    }

    // ---- QK^T: S strip (16x64) = 4 MFMAs ----
    short8 aq = *(const short8*)(qkv + (size_t)(m_base + wv * 16 + l15) * 768 + h * 32 + quad * 8);
    f32x4 c[4];
#pragma unroll
    for (int j = 0; j < 4; j++) {
        short8 bk = *(const short8*)(qkv + (size_t)(m_base + j * 16 + l15) * 768 + 256 + h * 32 + quad * 8);
        f32x4 z = {0.0f, 0.0f, 0.0f, 0.0f};
        c[j] = __builtin_amdgcn_mfma_f32_16x16x32_bf16(aq, bk, z, 0, 0, 0);
    }

    // ---- softmax over keys (row = quad*4+reg, col = j*16+l15) ----
    const float scale = 0.17677669529663687f; // 1/sqrt(32)
    float sm[4];
#pragma unroll
    for (int r = 0; r < 4; r++) {
        float m0 = -1e30f;
#pragma unroll
        for (int j = 0; j < 4; j++) { c[j][r] *= scale; m0 = fmaxf(m0, c[j][r]); }
#pragma unroll
        for (int d = 1; d < 16; d <<= 1) m0 = fmaxf(m0, __shfl_xor(m0, d, 64));
        float s0 = 0.0f;
#pragma unroll
        for (int j = 0; j < 4; j++) { float e = __expf(c[j][r] - m0); c[j][r] = e; s0 += e; }
#pragma unroll
        for (int d = 1; d < 16; d <<= 1) s0 += __shfl_xor(s0, d, 64);
        sm[r] = __builtin_amdgcn_rcpf(s0);
    }

    // ---- write P (bf16) to LDS ----
#pragma unroll
    for (int r = 0; r < 4; r++) {
        const int prow = wv * 16 + quad * 4 + r;
#pragma unroll
        for (int j = 0; j < 4; j++)
            Ps[prow * 72 + j * 16 + l15] = f2b(c[j][r] * sm[r]);
    }
    __syncthreads();

    // ---- PV: O strip (16x32) = 4 MFMAs ----
    short8 ap0 = *(const short8*)&Ps[(wv * 16 + l15) * 72 + quad * 8];
    short8 ap1 = *(const short8*)&Ps[(wv * 16 + l15) * 72 + 32 + quad * 8];
    f32x4 o[2];
#pragma unroll
    for (int nt = 0; nt < 2; nt++) {
        short8 bv0 = *(const short8*)&Vt[(nt * 16 + l15) * 72 + quad * 8];
        short8 bv1 = *(const short8*)&Vt[(nt * 16 + l15) * 72 + 32 + quad * 8];
        f32x4 z = {0.0f, 0.0f, 0.0f, 0.0f};
        o[nt] = __builtin_amdgcn_mfma_f32_16x16x32_bf16(ap0, bv0, z, 0, 0, 0);
        o[nt] = __builtin_amdgcn_mfma_f32_16x16x32_bf16(ap1, bv1, o[nt], 0, 0, 0);
    }

    // ---- write O (bf16) ----
#pragma unroll
    for (int nt = 0; nt < 2; nt++) {
#pragma unroll
        for (int r = 0; r < 4; r++) {
            const int row = m_base + wv * 16 + quad * 4 + r;
            out[(size_t)row * 256 + h * 32 + nt * 16 + l15] = f2b(o[nt][r]);
        }
    }
}

// ---------------------------------------------------------------------------
// Workspace layout (bytes), total ~186.5 MB (unchanged).
// ---------------------------------------------------------------------------
extern "C" void kernel_launch(void* const* d_in, const int* in_sizes, int n_in,
                              void* d_out, int out_size, void* d_ws, size_t ws_size,
                              hipStream_t stream)
{
    const float* x      = (const float*)d_in[0];
    const float* conv_w = (const float*)d_in[1];
    const float* conv_b = (const float*)d_in[2];
    const float* ln_w   = (const float*)d_in[3];
    const float* ln_b   = (const float*)d_in[4];
    const float* qkv_w  = (const float*)d_in[5];
    const float* qkv_b  = (const float*)d_in[6];
    const float* proj_w = (const float*)d_in[7];
    const float* proj_b = (const float*)d_in[8];
    const float* ff_w1  = (const float*)d_in[9];
    const float* ff_b1  = (const float*)d_in[10];
    const float* ff_w2  = (const float*)d_in[11];
    const float* ff_b2  = (const float*)d_in[12];
    float* out = (float*)d_out;

    char* ws = (char*)d_ws;
    unsigned short* xb    = (unsigned short*)(ws);                 // SLOT_A
    unsigned short* hidb  = (unsigned short*)(ws);                 // SLOT_A reuse
    float*          h0    = (float*)(ws + 67108864);               // SLOT_B
    unsigned short* qkvb  = (unsigned short*)(ws + 67108864);      // SLOT_B reuse
    float*          pe_t  = (float*)(ws + 100663296);              // SLOT_B tail
    float*          h1f   = (float*)(ws + 117440512);
    unsigned short* h1b   = (unsigned short*)(ws + 150994944);     // SLOT_C
    unsigned short* aob   = (unsigned short*)(ws + 150994944);     // SLOT_C reuse
    unsigned short* f1b   = (unsigned short*)(ws + 167772160);     // SLOT_D
    unsigned short* h2b   = (unsigned short*)(ws + 167772160);     // SLOT_D reuse
    unsigned short* wbase = (unsigned short*)(ws + 184549376);
    unsigned short* conv_wb = wbase;                 // 196608
    unsigned short* qkv_wb  = wbase + 196608;        // 196608
    unsigned short* proj_wb = wbase + 393216;        // 65536
    unsigned short* ff_w1b  = wbase + 458752;        // 262144
    unsigned short* ff_w2b  = wbase + 720896;        // 262144

    const int M = M_TOK;
    dim3 blk(256);

    // K0: conversions + PE table
    cvt_f2b_kernel<<<dim3(25165824 / 1024), blk, 0, stream>>>(x, xb, 25165824);
    cvt_weights_kernel<<<dim3(960), blk, 0, stream>>>(
        conv_w, qkv_w, proj_w, ff_w1, ff_w2,
        conv_wb, qkv_wb, proj_wb, ff_w1b, ff_w2b);
    pe_init_kernel<<<dim3(1024), blk, 0, stream>>>(pe_t);

    // K1: patch embed -> h0 (fp32)
    patch_mfma_kernel<<<dim3(M / 128, 2), blk, 0, stream>>>(xb, conv_wb, conv_b, h0);
    // K2: LN + PE -> h1f (fp32 residual) + h1b (bf16)
    ln_pe_kernel<<<dim3(M), blk, 0, stream>>>(h0, ln_w, ln_b, pe_t, h1f, h1b);
    // K3: FFN1a: gelu(h1 @ w1^T + b1) -> hidb (bf16)
    mfma_gemm_kernel<true, false, false, true><<<dim3(M / 128, 8), blk, 0, stream>>>(
        h1b, ff_w1b, ff_b1, nullptr, nullptr, hidb, M, 1024, 256);
    // K4: FFN1b: hidb @ w2^T + b2 -> f1b (bf16)
    mfma_gemm_kernel<false, false, false, true><<<dim3(M / 128, 2), blk, 0, stream>>>(
        hidb, ff_w2b, ff_b2, nullptr, nullptr, f1b, M, 256, 1024);
    // K5: qkv: f1b @ qkv_w^T + qkv_b -> qkvb (bf16)
    mfma_gemm_kernel<false, false, false, true><<<dim3(M / 128, 6), blk, 0, stream>>>(
        f1b, qkv_wb, qkv_b, nullptr, nullptr, qkvb, M, 768, 256);
    // K6: windowed attention (MFMA): qkvb -> aob (bf16)
    attn_mfma_kernel<<<dim3(4096), blk, 0, stream>>>(qkvb, aob);
    // K7: proj + residual(h1f): aob @ proj_w^T + proj_b + h1f -> out + h2b
    mfma_gemm_kernel<false, true, true, true><<<dim3(M / 128, 2), blk, 0, stream>>>(
        aob, proj_wb, proj_b, h1f, out, h2b, M, 256, 256);
    // K8: FFN2a: gelu(h2b @ w1^T + b1) -> hidb (bf16)
    mfma_gemm_kernel<true, false, false, true><<<dim3(M / 128, 8), blk, 0, stream>>>(
        h2b, ff_w1b, ff_b1, nullptr, nullptr, hidb, M, 1024, 256);
    // K9: FFN2b + final residual: hidb @ w2^T + b2 + out -> out
    mfma_gemm_kernel<false, true, true, false><<<dim3(M / 128, 2), blk, 0, stream>>>(
        hidb, ff_w2b, ff_b2, out, out, nullptr, M, 256, 1024);
}

// Round 7
// 417.812 us; speedup vs baseline: 1.4840x; 1.4840x over previous
//
#include <hip/hip_runtime.h>
#include <math.h>

// ============================================================================
// ViT block on MI355X — Round 9 (resubmit; prior bench failed on infra):
//   * Revert round-8 no-LDS experiment (it amplified read AND write traffic).
//   * Base = round 6 (best, 406 µs): dbuf LDS + counted vmcnt + 2 barriers.
//   * Change: BK=64 -> BK=32 dbuf => LDS 64->32 KB/block => 5 blocks/CU
//     (occupancy 20%->~60%): cross-block overlap hides stage latency that
//     depth-1 prefetch cannot (per-tile compute ~310cyc << HBM ~900cyc).
//   * Swizzle rederived for 64B rows (2-bit chunk XOR), vmcnt(4) counting.
//   * Attention, LN+PE, cvt, workspace unchanged.
// ============================================================================

#define M_TOK 32768

typedef __attribute__((ext_vector_type(8))) short  short8;   // 8 bf16 (4 VGPRs)
typedef __attribute__((ext_vector_type(4))) float  f32x4;
typedef __attribute__((ext_vector_type(8))) unsigned short us8v;
typedef __attribute__((ext_vector_type(4))) unsigned short us4v;

__device__ __forceinline__ unsigned short f2b(float f) {
    union { float f; unsigned u; } c; c.f = f;
    unsigned r = c.u + 0x7fffu + ((c.u >> 16) & 1u);   // RNE
    return (unsigned short)(r >> 16);
}
__device__ __forceinline__ float gelu_fast(float x) {
    // 0.5x(1+tanh(c0(x+0.044715x^3))) == x * sigmoid(2*c0*(x+0.044715x^3))
    const float c0 = 0.7978845608028654f;            // sqrt(2/pi)
    const float c1 = 0.044715f * 0.7978845608028654f;
    float z = x * (c0 + c1 * x * x);
    float e = __expf(-2.0f * z);
    return x * __builtin_amdgcn_rcpf(1.0f + e);
}
// async global->LDS, 16B per lane; lds dest must be wave-uniform base (+lane*16 by HW)
__device__ __forceinline__ void load_lds16(const unsigned short* g, void* lds) {
    __builtin_amdgcn_global_load_lds(
        (const __attribute__((address_space(1))) unsigned int*)g,
        (__attribute__((address_space(3))) unsigned int*)lds, 16, 0, 0);
}

// ---------------------------------------------------------------------------
// fp32 -> bf16 convert (n % 4 == 0) — used for the big image tensor only
// ---------------------------------------------------------------------------
__global__ __launch_bounds__(256) void cvt_f2b_kernel(
    const float* __restrict__ in, unsigned short* __restrict__ out, int n)
{
    int i = (blockIdx.x * 256 + threadIdx.x) * 4;
    if (i >= n) return;
    float4 v = *(const float4*)(in + i);
    us4v o;
    o[0] = f2b(v.x); o[1] = f2b(v.y); o[2] = f2b(v.z); o[3] = f2b(v.w);
    *(us4v*)(out + i) = o;
}

// ---------------------------------------------------------------------------
// All 5 weight tensors converted in ONE launch (ranges in 1024-elem blocks)
// ---------------------------------------------------------------------------
__global__ __launch_bounds__(256) void cvt_weights_kernel(
    const float* __restrict__ s0, const float* __restrict__ s1,
    const float* __restrict__ s2, const float* __restrict__ s3,
    const float* __restrict__ s4,
    unsigned short* __restrict__ d0, unsigned short* __restrict__ d1,
    unsigned short* __restrict__ d2, unsigned short* __restrict__ d3,
    unsigned short* __restrict__ d4)
{
    const int bid = blockIdx.x;
    const float* src; unsigned short* dst; int off;
    if      (bid < 192) { src = s0; dst = d0; off = bid; }
    else if (bid < 384) { src = s1; dst = d1; off = bid - 192; }
    else if (bid < 448) { src = s2; dst = d2; off = bid - 384; }
    else if (bid < 704) { src = s3; dst = d3; off = bid - 448; }
    else                { src = s4; dst = d4; off = bid - 704; }
    const int i = off * 1024 + threadIdx.x * 4;
    float4 v = *(const float4*)(src + i);
    us4v o;
    o[0] = f2b(v.x); o[1] = f2b(v.y); o[2] = f2b(v.z); o[3] = f2b(v.w);
    *(us4v*)(dst + i) = o;
}

// ---------------------------------------------------------------------------
// Sinusoidal PE table: pe[pos][d], pos<1024, d<256.
// ---------------------------------------------------------------------------
__global__ __launch_bounds__(256) void pe_init_kernel(float* __restrict__ pe)
{
    const int pos = blockIdx.x;
    const int d   = threadIdx.x;
    const int ieven = d & ~1;
    float div = expf(-9.210340371976184f * (float)ieven * (1.0f / 256.0f));
    float ang = (float)pos * div;
    pe[pos * 256 + d] = (d & 1) ? cosf(ang) : sinf(ang);
}

// ---------------------------------------------------------------------------
// MFMA GEMM: C = A (MxK) . W^T (NxK) + bias (+gelu/res)
// 128x128 tile, BK=32, 256 thr = 4 waves 2x2, dbuf LDS 32 KB total.
// Per-buffer [128][32] bf16, 64B rows of 4 x 16B chunks, XOR swizzle:
//   stored chunk c' of row holds data chunk c' ^ (row&3).
// Staging round r (2/tensor/tile): wave wv lane l -> linear byte
//   r*4096 + wv*1024 + l*16 -> row = r*64 + wv*16 + (l>>2), chunk = l&3;
//   source k-chunk pre-swizzled: skk = ((l&3) ^ ((l>>2)&3)) * 8.
// Read: row = wr+i*16+l15 -> chunk = quad ^ (l15&3) (round-trips exactly).
// Pipeline: round-6 schedule, counted vmcnt(4) (4 loads in flight / tile).
// ---------------------------------------------------------------------------
template<bool GELU, bool RES, bool WF32, bool WB16>
__global__ __launch_bounds__(256) void mfma_gemm_kernel(
    const unsigned short* __restrict__ A, const unsigned short* __restrict__ W,
    const float* __restrict__ bias, const float* __restrict__ res,
    float* __restrict__ outF, unsigned short* __restrict__ outB,
    int M, int N, int K)
{
    __shared__ unsigned short As[2 * 128 * 32];   // 16 KB (2 buffers)
    __shared__ unsigned short Ws[2 * 128 * 32];   // 16 KB

    const int t    = threadIdx.x;
    const int m0   = blockIdx.x * 128;
    const int n0   = blockIdx.y * 128;
    const int wv   = t >> 6, lane = t & 63;
    const int wr   = (wv >> 1) * 64, wc = (wv & 1) * 64;
    const int l15  = lane & 15, quad = lane >> 4;

    f32x4 acc[4][4];
#pragma unroll
    for (int i = 0; i < 4; i++)
#pragma unroll
        for (int j = 0; j < 4; j++)
#pragma unroll
            for (int r = 0; r < 4; r++) acc[i][j][r] = 0.0f;

    // staging map (round r): row = r*64 + wv*16 + (lane>>2), swizzled k-chunk
    const int srow = wv * 16 + (lane >> 2);
    const int skk  = (((lane & 3) ^ ((lane >> 2) & 3)) * 8);
    const unsigned short* gA = A + (size_t)(m0 + srow) * K + skk;
    const unsigned short* gW = W + (size_t)(n0 + srow) * K + skk;
    char* lA = (char*)As + wv * 1024;      // + buf*8192 + r*4096
    char* lW = (char*)Ws + wv * 1024;

    const int cswz = (quad ^ (l15 & 3)) * 8;   // read-side chunk (shorts)
    const int nt   = K >> 5;                   // 8 or 32 (always even)

#define GSTAGE(tt, BUFOFF)                                                     \
    {                                                                          \
        const int kk = (tt) << 5;                                              \
        _Pragma("unroll")                                                      \
        for (int r = 0; r < 2; r++) {                                          \
            load_lds16(gA + (size_t)(r * 64) * K + kk, lA + (BUFOFF) + r * 4096); \
            load_lds16(gW + (size_t)(r * 64) * K + kk, lW + (BUFOFF) + r * 4096); \
        }                                                                      \
    }

#define GCOMPUTE(BUFOFF)                                                       \
    {                                                                          \
        const unsigned short* Ab = (const unsigned short*)((const char*)As + (BUFOFF)); \
        const unsigned short* Wb = (const unsigned short*)((const char*)Ws + (BUFOFF)); \
        short8 af[4], wf[4];                                                   \
        _Pragma("unroll")                                                      \
        for (int i = 0; i < 4; i++)                                            \
            af[i] = *(const short8*)&Ab[(wr + i * 16 + l15) * 32 + cswz];      \
        _Pragma("unroll")                                                      \
        for (int j = 0; j < 4; j++)                                            \
            wf[j] = *(const short8*)&Wb[(wc + j * 16 + l15) * 32 + cswz];      \
        _Pragma("unroll")                                                      \
        for (int i = 0; i < 4; i++)                                            \
            _Pragma("unroll")                                                  \
            for (int j = 0; j < 4; j++)                                        \
                acc[i][j] = __builtin_amdgcn_mfma_f32_16x16x32_bf16(           \
                    af[i], wf[j], acc[i][j], 0, 0, 0);                         \
    }

    GSTAGE(0, 0);                               // prologue: tile 0 -> buf0
    for (int tt = 0; tt < nt; tt += 2) {
        // ---- sub-iter A: stage tile tt+1 -> buf1, compute buf0 ----
        GSTAGE(tt + 1, 8192);
        asm volatile("s_waitcnt vmcnt(4)" ::: "memory");   // tile tt landed
        __builtin_amdgcn_s_barrier();
        __builtin_amdgcn_sched_barrier(0);
        GCOMPUTE(0);
        __builtin_amdgcn_s_barrier();
        // ---- sub-iter B: stage tile tt+2 -> buf0, compute buf1 ----
        if (tt + 2 < nt) {
            GSTAGE(tt + 2, 0);
            asm volatile("s_waitcnt vmcnt(4)" ::: "memory");
        } else {
            asm volatile("s_waitcnt vmcnt(0)" ::: "memory");
        }
        __builtin_amdgcn_s_barrier();
        __builtin_amdgcn_sched_barrier(0);
        GCOMPUTE(8192);
        __builtin_amdgcn_s_barrier();
    }
#undef GSTAGE
#undef GCOMPUTE

#pragma unroll
    for (int i = 0; i < 4; i++) {
        const int gr = m0 + wr + i * 16 + quad * 4;
#pragma unroll
        for (int j = 0; j < 4; j++) {
            const int gc = n0 + wc + j * 16 + l15;
            const float bv = bias[gc];
#pragma unroll
            for (int r = 0; r < 4; r++) {
                float v = acc[i][j][r] + bv;
                if (GELU) v = gelu_fast(v);
                if (RES)  v += res[(size_t)(gr + r) * N + gc];
                if (WF32) outF[(size_t)(gr + r) * N + gc] = v;
                if (WB16) outB[(size_t)(gr + r) * N + gc] = f2b(v);
            }
        }
    }
}

// ---------------------------------------------------------------------------
// Patch-embed MFMA GEMM: A gathered from bf16 image xb, W = conv_w bf16.
// Same BK=32 dbuf pipeline; A source is a per-lane gather. nt = 24 (even).
// ---------------------------------------------------------------------------
__global__ __launch_bounds__(256) void patch_mfma_kernel(
    const unsigned short* __restrict__ xb, const unsigned short* __restrict__ W,
    const float* __restrict__ bias, float* __restrict__ outF)
{
    __shared__ unsigned short As[2 * 128 * 32];
    __shared__ unsigned short Ws[2 * 128 * 32];

    const int t    = threadIdx.x;
    const int m0   = blockIdx.x * 128;
    const int n0   = blockIdx.y * 128;
    const int wv   = t >> 6, lane = t & 63;
    const int wr   = (wv >> 1) * 64, wc = (wv & 1) * 64;
    const int l15  = lane & 15, quad = lane >> 4;

    f32x4 acc[4][4];
#pragma unroll
    for (int i = 0; i < 4; i++)
#pragma unroll
        for (int j = 0; j < 4; j++)
#pragma unroll
            for (int r = 0; r < 4; r++) acc[i][j][r] = 0.0f;

    const int srow = wv * 16 + (lane >> 2);
    const int skk  = (((lane & 3) ^ ((lane >> 2) & 3)) * 8);  // swizzled k-chunk
    size_t xoff[2];
#pragma unroll
    for (int r = 0; r < 2; r++) {
        const int m  = m0 + r * 64 + srow;
        const int b  = m >> 10;
        const int idx = m & 1023;
        const int hh = idx >> 5, ww = idx & 31;
        xoff[r] = ((size_t)(b * 3) * 512 + (size_t)(hh * 16)) * 512 + ww * 16;
    }
    const unsigned short* gW = W + (size_t)(n0 + srow) * 768 + skk;
    char* lA = (char*)As + wv * 1024;
    char* lW = (char*)Ws + wv * 1024;

    const int cswz = (quad ^ (l15 & 3)) * 8;

#define PSTAGE(tt, BUFOFF)                                                     \
    {                                                                          \
        const int kk = ((tt) << 5) + skk;   /* 8-aligned, within one px row */ \
        const int c  = kk >> 8;                                                \
        const int ph = (kk >> 4) & 15;                                         \
        const int pw = kk & 15;                                                \
        const size_t koff = (size_t)c * 262144 + (size_t)ph * 512 + pw;        \
        _Pragma("unroll")                                                      \
        for (int r = 0; r < 2; r++) {                                          \
            load_lds16(xb + xoff[r] + koff, lA + (BUFOFF) + r * 4096);         \
            load_lds16(gW + (size_t)(r * 64) * 768 + ((tt) << 5),              \
                       lW + (BUFOFF) + r * 4096);                              \
        }                                                                      \
    }

#define PCOMPUTE(BUFOFF)                                                       \
    {                                                                          \
        const unsigned short* Ab = (const unsigned short*)((const char*)As + (BUFOFF)); \
        const unsigned short* Wb = (const unsigned short*)((const char*)Ws + (BUFOFF)); \
        short8 af[4], wf[4];                                                   \
        _Pragma("unroll")                                                      \
        for (int i = 0; i < 4; i++)                                            \
            af[i] = *(const short8*)&Ab[(wr + i * 16 + l15) * 32 + cswz];      \
        _Pragma("unroll")                                                      \
        for (int j = 0; j < 4; j++)                                            \
            wf[j] = *(const short8*)&Wb[(wc + j * 16 + l15) * 32 + cswz];      \
        _Pragma("unroll")                                                      \
        for (int i = 0; i < 4; i++)                                            \
            _Pragma("unroll")                                                  \
            for (int j = 0; j < 4; j++)                                        \
                acc[i][j] = __builtin_amdgcn_mfma_f32_16x16x32_bf16(           \
                    af[i], wf[j], acc[i][j], 0, 0, 0);                         \
    }

    PSTAGE(0, 0);
    for (int tt = 0; tt < 24; tt += 2) {
        PSTAGE(tt + 1, 8192);
        asm volatile("s_waitcnt vmcnt(4)" ::: "memory");
        __builtin_amdgcn_s_barrier();
        __builtin_amdgcn_sched_barrier(0);
        PCOMPUTE(0);
        __builtin_amdgcn_s_barrier();
        if (tt + 2 < 24) {
            PSTAGE(tt + 2, 0);
            asm volatile("s_waitcnt vmcnt(4)" ::: "memory");
        } else {
            asm volatile("s_waitcnt vmcnt(0)" ::: "memory");
        }
        __builtin_amdgcn_s_barrier();
        __builtin_amdgcn_sched_barrier(0);
        PCOMPUTE(8192);
        __builtin_amdgcn_s_barrier();
    }
#undef PSTAGE
#undef PCOMPUTE

#pragma unroll
    for (int i = 0; i < 4; i++) {
        const int gr = m0 + wr + i * 16 + quad * 4;
#pragma unroll
        for (int j = 0; j < 4; j++) {
            const int gc = n0 + wc + j * 16 + l15;
            const float bv = bias[gc];
#pragma unroll
            for (int r = 0; r < 4; r++)
                outF[(size_t)(gr + r) * 256 + gc] = acc[i][j][r] + bv;
        }
    }
}

// ---------------------------------------------------------------------------
// LayerNorm + PE (table lookup). One block = one token (256 features).
// ---------------------------------------------------------------------------
__global__ __launch_bounds__(256) void ln_pe_kernel(
    const float* __restrict__ in, const float* __restrict__ w,
    const float* __restrict__ b, const float* __restrict__ pe_t,
    float* __restrict__ outF, unsigned short* __restrict__ outB)
{
    const int m = blockIdx.x;
    const int d = threadIdx.x;
    float v = in[(size_t)m * 256 + d];

    float s = v, s2 = v * v;
#pragma unroll
    for (int off = 32; off > 0; off >>= 1) {
        s  += __shfl_down(s,  off, 64);
        s2 += __shfl_down(s2, off, 64);
    }
    __shared__ float ss[4], ss2[4], stats[2];
    const int lane = d & 63, wid = d >> 6;
    if (lane == 0) { ss[wid] = s; ss2[wid] = s2; }
    __syncthreads();
    if (d == 0) {
        float a  = ss[0] + ss[1] + ss[2] + ss[3];
        float a2 = ss2[0] + ss2[1] + ss2[2] + ss2[3];
        float mean = a * (1.0f / 256.0f);
        float var  = a2 * (1.0f / 256.0f) - mean * mean;
        stats[0] = mean;
        stats[1] = rsqrtf(var + 1e-5f);
    }
    __syncthreads();
    const float mean = stats[0], rstd = stats[1];

    const int pos = m & 1023;
    float pe = pe_t[pos * 256 + d];

    float o = (v - mean) * rstd * w[d] + b[d] + pe;
    outF[(size_t)m * 256 + d] = o;
    outB[(size_t)m * 256 + d] = f2b(o);
}

// ---------------------------------------------------------------------------
// MFMA windowed attention. One block = one (batch, window, head).
// ---------------------------------------------------------------------------
__global__ __launch_bounds__(256) void attn_mfma_kernel(
    const unsigned short* __restrict__ qkv, unsigned short* __restrict__ out)
{
    __shared__ unsigned short Ps[64 * 72];   // P, stride 72 (b128-aligned, padded)
    __shared__ unsigned short Vt[32 * 72];   // V^T [headdim][key]

    const int blk = blockIdx.x;        // 0..4095
    const int h = blk & 7;
    const int w = (blk >> 3) & 15;
    const int b = blk >> 7;
    const int m_base = b * 1024 + w * 64;

    const int t = threadIdx.x;
    const int wv = t >> 6, lane = t & 63;
    const int l15 = lane & 15, quad = lane >> 4;

    // ---- stage V^T (cooperative, 8 elems/thread) ----
    {
        const int row = t >> 2;             // key 0..63
        const int c0  = (t & 3) * 8;        // headdim chunk
        const unsigned short* src = qkv + (size_t)(m_base + row) * 768 + 512 + h * 32 + c0;
        us8v v = *(const us8v*)src;
#pragma unroll
        for (int j = 0; j < 8; j++) Vt[(c0 + j) * 72 + row] = v[j];
    }

    // ---- QK^T: S strip (16x64) = 4 MFMAs ----
    short8 aq = *(const short8*)(qkv + (size_t)(m_base + wv * 16 + l15) * 768 + h * 32 + quad * 8);
    f32x4 c[4];
#pragma unroll
    for (int j = 0; j < 4; j++) {
        short8 bk = *(const short8*)(qkv + (size_t)(m_base + j * 16 + l15) * 768 + 256 + h * 32 + quad * 8);
        f32x4 z = {0.0f, 0.0f, 0.0f, 0.0f};
        c[j] = __builtin_amdgcn_mfma_f32_16x16x32_bf16(aq, bk, z, 0, 0, 0);
    }

    // ---- softmax over keys (row = quad*4+reg, col = j*16+l15) ----
    const float scale = 0.17677669529663687f; // 1/sqrt(32)
    float sm[4];
#pragma unroll
    for (int r = 0; r < 4; r++) {
        float m0 = -1e30f;
#pragma unroll
        for (int j = 0; j < 4; j++) { c[j][r] *= scale; m0 = fmaxf(m0, c[j][r]); }
#pragma unroll
        for (int d = 1; d < 16; d <<= 1) m0 = fmaxf(m0, __shfl_xor(m0, d, 64));
        float s0 = 0.0f;
#pragma unroll
        for (int j = 0; j < 4; j++) { float e = __expf(c[j][r] - m0); c[j][r] = e; s0 += e; }
#pragma unroll
        for (int d = 1; d < 16; d <<= 1) s0 += __shfl_xor(s0, d, 64);
        sm[r] = __builtin_amdgcn_rcpf(s0);
    }

    // ---- write P (bf16) to LDS ----
#pragma unroll
    for (int r = 0; r < 4; r++) {
        const int prow = wv * 16 + quad * 4 + r;
#pragma unroll
        for (int j = 0; j < 4; j++)
            Ps[prow * 72 + j * 16 + l15] = f2b(c[j][r] * sm[r]);
    }
    __syncthreads();

    // ---- PV: O strip (16x32) = 4 MFMAs ----
    short8 ap0 = *(const short8*)&Ps[(wv * 16 + l15) * 72 + quad * 8];
    short8 ap1 = *(const short8*)&Ps[(wv * 16 + l15) * 72 + 32 + quad * 8];
    f32x4 o[2];
#pragma unroll
    for (int nt = 0; nt < 2; nt++) {
        short8 bv0 = *(const short8*)&Vt[(nt * 16 + l15) * 72 + quad * 8];
        short8 bv1 = *(const short8*)&Vt[(nt * 16 + l15) * 72 + 32 + quad * 8];
        f32x4 z = {0.0f, 0.0f, 0.0f, 0.0f};
        o[nt] = __builtin_amdgcn_mfma_f32_16x16x32_bf16(ap0, bv0, z, 0, 0, 0);
        o[nt] = __builtin_amdgcn_mfma_f32_16x16x32_bf16(ap1, bv1, o[nt], 0, 0, 0);
    }

    // ---- write O (bf16) ----
#pragma unroll
    for (int nt = 0; nt < 2; nt++) {
#pragma unroll
        for (int r = 0; r < 4; r++) {
            const int row = m_base + wv * 16 + quad * 4 + r;
            out[(size_t)row * 256 + h * 32 + nt * 16 + l15] = f2b(o[nt][r]);
        }
    }
}

// ---------------------------------------------------------------------------
// Workspace layout (bytes), total ~186.5 MB (unchanged).
// ---------------------------------------------------------------------------
extern "C" void kernel_launch(void* const* d_in, const int* in_sizes, int n_in,
                              void* d_out, int out_size, void* d_ws, size_t ws_size,
                              hipStream_t stream)
{
    const float* x      = (const float*)d_in[0];
    const float* conv_w = (const float*)d_in[1];
    const float* conv_b = (const float*)d_in[2];
    const float* ln_w   = (const float*)d_in[3];
    const float* ln_b   = (const float*)d_in[4];
    const float* qkv_w  = (const float*)d_in[5];
    const float* qkv_b  = (const float*)d_in[6];
    const float* proj_w = (const float*)d_in[7];
    const float* proj_b = (const float*)d_in[8];
    const float* ff_w1  = (const float*)d_in[9];
    const float* ff_b1  = (const float*)d_in[10];
    const float* ff_w2  = (const float*)d_in[11];
    const float* ff_b2  = (const float*)d_in[12];
    float* out = (float*)d_out;

    char* ws = (char*)d_ws;
    unsigned short* xb    = (unsigned short*)(ws);                 // SLOT_A
    unsigned short* hidb  = (unsigned short*)(ws);                 // SLOT_A reuse
    float*          h0    = (float*)(ws + 67108864);               // SLOT_B
    unsigned short* qkvb  = (unsigned short*)(ws + 67108864);      // SLOT_B reuse
    float*          pe_t  = (float*)(ws + 100663296);              // SLOT_B tail
    float*          h1f   = (float*)(ws + 117440512);
    unsigned short* h1b   = (unsigned short*)(ws + 150994944);     // SLOT_C
    unsigned short* aob   = (unsigned short*)(ws + 150994944);     // SLOT_C reuse
    unsigned short* f1b   = (unsigned short*)(ws + 167772160);     // SLOT_D
    unsigned short* h2b   = (unsigned short*)(ws + 167772160);     // SLOT_D reuse
    unsigned short* wbase = (unsigned short*)(ws + 184549376);
    unsigned short* conv_wb = wbase;                 // 196608
    unsigned short* qkv_wb  = wbase + 196608;        // 196608
    unsigned short* proj_wb = wbase + 393216;        // 65536
    unsigned short* ff_w1b  = wbase + 458752;        // 262144
    unsigned short* ff_w2b  = wbase + 720896;        // 262144

    const int M = M_TOK;
    dim3 blk(256);

    // K0: conversions + PE table
    cvt_f2b_kernel<<<dim3(25165824 / 1024), blk, 0, stream>>>(x, xb, 25165824);
    cvt_weights_kernel<<<dim3(960), blk, 0, stream>>>(
        conv_w, qkv_w, proj_w, ff_w1, ff_w2,
        conv_wb, qkv_wb, proj_wb, ff_w1b, ff_w2b);
    pe_init_kernel<<<dim3(1024), blk, 0, stream>>>(pe_t);

    // K1: patch embed -> h0 (fp32)
    patch_mfma_kernel<<<dim3(M / 128, 2), blk, 0, stream>>>(xb, conv_wb, conv_b, h0);
    // K2: LN + PE -> h1f (fp32 residual) + h1b (bf16)
    ln_pe_kernel<<<dim3(M), blk, 0, stream>>>(h0, ln_w, ln_b, pe_t, h1f, h1b);
    // K3: FFN1a: gelu(h1 @ w1^T + b1) -> hidb (bf16)
    mfma_gemm_kernel<true, false, false, true><<<dim3(M / 128, 8), blk, 0, stream>>>(
        h1b, ff_w1b, ff_b1, nullptr, nullptr, hidb, M, 1024, 256);
    // K4: FFN1b: hidb @ w2^T + b2 -> f1b (bf16)
    mfma_gemm_kernel<false, false, false, true><<<dim3(M / 128, 2), blk, 0, stream>>>(
        hidb, ff_w2b, ff_b2, nullptr, nullptr, f1b, M, 256, 1024);
    // K5: qkv: f1b @ qkv_w^T + qkv_b -> qkvb (bf16)
    mfma_gemm_kernel<false, false, false, true><<<dim3(M / 128, 6), blk, 0, stream>>>(
        f1b, qkv_wb, qkv_b, nullptr, nullptr, qkvb, M, 768, 256);
    // K6: windowed attention (MFMA): qkvb -> aob (bf16)
    attn_mfma_kernel<<<dim3(4096), blk, 0, stream>>>(qkvb, aob);
    // K7: proj + residual(h1f): aob @ proj_w^T + proj_b + h1f -> out + h2b
    mfma_gemm_kernel<false, true, true, true><<<dim3(M / 128, 2), blk, 0, stream>>>(
        aob, proj_wb, proj_b, h1f, out, h2b, M, 256, 256);
    // K8: FFN2a: gelu(h2b @ w1^T + b1) -> hidb (bf16)
    mfma_gemm_kernel<true, false, false, true><<<dim3(M / 128, 8), blk, 0, stream>>>(
        h2b, ff_w1b, ff_b1, nullptr, nullptr, hidb, M, 1024, 256);
    // K9: FFN2b + final residual: hidb @ w2^T + b2 + out -> out
    mfma_gemm_kernel<false, true, true, false><<<dim3(M / 128, 2), blk, 0, stream>>>(
        hidb, ff_w2b, ff_b2, out, out, nullptr, M, 256, 1024);
}

// Round 8
// 394.294 us; speedup vs baseline: 1.5725x; 1.0596x over previous
//
#include <hip/hip_runtime.h>
#include <math.h>

// ============================================================================
// ViT block on MI355X — Round 10:
//   * Base = round 6 (best, 406 µs): BK=64 dbuf LDS + counted vmcnt(4) +
//     2 barriers/tile. Schedule unchanged.
//   * Change: GEMM/patch blocks 256 -> 512 threads (8 waves, 2Mx4N, 64x32
//     per wave). Same 64 KB LDS, same 2 blocks/CU, but 4 waves/SIMD (was 2):
//     doubles latency-hiding TLP without adding barriers (R9's mistake).
//     Per-thread epilogue halves (32 outs), acc 32 VGPR + 48 frag.
//   * Attention, LN+PE, cvt, workspace unchanged.
// ============================================================================

#define M_TOK 32768

typedef __attribute__((ext_vector_type(8))) short  short8;   // 8 bf16 (4 VGPRs)
typedef __attribute__((ext_vector_type(4))) float  f32x4;
typedef __attribute__((ext_vector_type(8))) unsigned short us8v;
typedef __attribute__((ext_vector_type(4))) unsigned short us4v;

__device__ __forceinline__ unsigned short f2b(float f) {
    union { float f; unsigned u; } c; c.f = f;
    unsigned r = c.u + 0x7fffu + ((c.u >> 16) & 1u);   // RNE
    return (unsigned short)(r >> 16);
}
__device__ __forceinline__ float gelu_fast(float x) {
    // 0.5x(1+tanh(c0(x+0.044715x^3))) == x * sigmoid(2*c0*(x+0.044715x^3))
    const float c0 = 0.7978845608028654f;            // sqrt(2/pi)
    const float c1 = 0.044715f * 0.7978845608028654f;
    float z = x * (c0 + c1 * x * x);
    float e = __expf(-2.0f * z);
    return x * __builtin_amdgcn_rcpf(1.0f + e);
}
// async global->LDS, 16B per lane; lds dest must be wave-uniform base (+lane*16 by HW)
__device__ __forceinline__ void load_lds16(const unsigned short* g, void* lds) {
    __builtin_amdgcn_global_load_lds(
        (const __attribute__((address_space(1))) unsigned int*)g,
        (__attribute__((address_space(3))) unsigned int*)lds, 16, 0, 0);
}

// ---------------------------------------------------------------------------
// fp32 -> bf16 convert (n % 4 == 0) — used for the big image tensor only
// ---------------------------------------------------------------------------
__global__ __launch_bounds__(256) void cvt_f2b_kernel(
    const float* __restrict__ in, unsigned short* __restrict__ out, int n)
{
    int i = (blockIdx.x * 256 + threadIdx.x) * 4;
    if (i >= n) return;
    float4 v = *(const float4*)(in + i);
    us4v o;
    o[0] = f2b(v.x); o[1] = f2b(v.y); o[2] = f2b(v.z); o[3] = f2b(v.w);
    *(us4v*)(out + i) = o;
}

// ---------------------------------------------------------------------------
// All 5 weight tensors converted in ONE launch (ranges in 1024-elem blocks)
// ---------------------------------------------------------------------------
__global__ __launch_bounds__(256) void cvt_weights_kernel(
    const float* __restrict__ s0, const float* __restrict__ s1,
    const float* __restrict__ s2, const float* __restrict__ s3,
    const float* __restrict__ s4,
    unsigned short* __restrict__ d0, unsigned short* __restrict__ d1,
    unsigned short* __restrict__ d2, unsigned short* __restrict__ d3,
    unsigned short* __restrict__ d4)
{
    const int bid = blockIdx.x;
    const float* src; unsigned short* dst; int off;
    if      (bid < 192) { src = s0; dst = d0; off = bid; }
    else if (bid < 384) { src = s1; dst = d1; off = bid - 192; }
    else if (bid < 448) { src = s2; dst = d2; off = bid - 384; }
    else if (bid < 704) { src = s3; dst = d3; off = bid - 448; }
    else                { src = s4; dst = d4; off = bid - 704; }
    const int i = off * 1024 + threadIdx.x * 4;
    float4 v = *(const float4*)(src + i);
    us4v o;
    o[0] = f2b(v.x); o[1] = f2b(v.y); o[2] = f2b(v.z); o[3] = f2b(v.w);
    *(us4v*)(dst + i) = o;
}

// ---------------------------------------------------------------------------
// Sinusoidal PE table: pe[pos][d], pos<1024, d<256.
// ---------------------------------------------------------------------------
__global__ __launch_bounds__(256) void pe_init_kernel(float* __restrict__ pe)
{
    const int pos = blockIdx.x;
    const int d   = threadIdx.x;
    const int ieven = d & ~1;
    float div = expf(-9.210340371976184f * (float)ieven * (1.0f / 256.0f));
    float ang = (float)pos * div;
    pe[pos * 256 + d] = (d & 1) ? cosf(ang) : sinf(ang);
}

// ---------------------------------------------------------------------------
// MFMA GEMM: C = A (MxK) . W^T (NxK) + bias (+gelu/res)
// 128x128 tile, BK=64, 512 thr = 8 waves (2 M-groups x 4 N-groups, 64x32
// per wave), double-buffered LDS (64 KB). Per-buffer [128][64] bf16,
// XOR swizzle: stored chunk c of row holds data chunk c ^ (row&7).
// Staging round s (2/tensor/tile): wave wv lane l -> linear byte
//   s*8192 + wv*1024 + l*16 -> row = s*64 + wv*8 + (l>>3), chunk = l&7;
//   source k-chunk pre-swizzled: skk = ((l&7) ^ ((l>>3)&7)) * 8.
// Read row & 7 == l15 & 7 -> chunk (kh*4+quad) ^ (l15&7). Round-trips exact.
// Pipeline: round-6 schedule — stage(t+1) -> vmcnt(4) -> bar -> compute(t)
// -> bar. 4 global_load_lds per thread-stage (2 A rounds + 2 W rounds).
// ---------------------------------------------------------------------------
template<bool GELU, bool RES, bool WF32, bool WB16>
__global__ __launch_bounds__(512) void mfma_gemm_kernel(
    const unsigned short* __restrict__ A, const unsigned short* __restrict__ W,
    const float* __restrict__ bias, const float* __restrict__ res,
    float* __restrict__ outF, unsigned short* __restrict__ outB,
    int M, int N, int K)
{
    __shared__ unsigned short As[2 * 128 * 64];
    __shared__ unsigned short Ws[2 * 128 * 64];

    const int t    = threadIdx.x;
    const int m0   = blockIdx.x * 128;
    const int n0   = blockIdx.y * 128;
    const int wv   = t >> 6, lane = t & 63;
    const int wr   = (wv >> 2) * 64;       // M-group: 0 or 64
    const int wc   = (wv & 3) * 32;        // N-group: 0,32,64,96
    const int l15  = lane & 15, quad = lane >> 4;

    f32x4 acc[4][2];
#pragma unroll
    for (int i = 0; i < 4; i++)
#pragma unroll
        for (int j = 0; j < 2; j++)
#pragma unroll
            for (int r = 0; r < 4; r++) acc[i][j][r] = 0.0f;

    // staging map (round s): row = s*64 + wv*8 + (lane>>3), swizzled k-chunk
    const int srow = wv * 8 + (lane >> 3);
    const int skk  = (((lane & 7) ^ ((lane >> 3) & 7)) * 8);
    const unsigned short* gA = A + (size_t)(m0 + srow) * K + skk;
    const unsigned short* gW = W + (size_t)(n0 + srow) * K + skk;
    char* lA = (char*)As + wv * 1024;      // + buf*16384 + s*8192
    char* lW = (char*)Ws + wv * 1024;

    const int cswz = (l15 & 7) * 8;        // read-side XOR (shorts)
    const int nt   = K >> 6;               // 4 or 16 (always even)

#define GSTAGE(tt, BUFOFF)                                                     \
    {                                                                          \
        const int kk = (tt) << 6;                                              \
        _Pragma("unroll")                                                      \
        for (int s = 0; s < 2; s++) {                                          \
            load_lds16(gA + (size_t)(s * 64) * K + kk, lA + (BUFOFF) + s * 8192); \
            load_lds16(gW + (size_t)(s * 64) * K + kk, lW + (BUFOFF) + s * 8192); \
        }                                                                      \
    }

#define GCOMPUTE(BUFOFF)                                                       \
    {                                                                          \
        const unsigned short* Ab = (const unsigned short*)((const char*)As + (BUFOFF)); \
        const unsigned short* Wb = (const unsigned short*)((const char*)Ws + (BUFOFF)); \
        _Pragma("unroll")                                                      \
        for (int kh = 0; kh < 2; kh++) {                                       \
            const int coff = (kh * 32 + quad * 8) ^ cswz;                      \
            short8 af[4], wf[2];                                               \
            _Pragma("unroll")                                                  \
            for (int i = 0; i < 4; i++)                                        \
                af[i] = *(const short8*)&Ab[(wr + i * 16 + l15) * 64 + coff];  \
            _Pragma("unroll")                                                  \
            for (int j = 0; j < 2; j++)                                        \
                wf[j] = *(const short8*)&Wb[(wc + j * 16 + l15) * 64 + coff];  \
            _Pragma("unroll")                                                  \
            for (int i = 0; i < 4; i++)                                        \
                _Pragma("unroll")                                              \
                for (int j = 0; j < 2; j++)                                    \
                    acc[i][j] = __builtin_amdgcn_mfma_f32_16x16x32_bf16(       \
                        af[i], wf[j], acc[i][j], 0, 0, 0);                     \
        }                                                                      \
    }

    GSTAGE(0, 0);                               // prologue: tile 0 -> buf0
    for (int tt = 0; tt < nt; tt += 2) {
        // ---- sub-iter A: stage tile tt+1 -> buf1, compute buf0 ----
        GSTAGE(tt + 1, 16384);
        asm volatile("s_waitcnt vmcnt(4)" ::: "memory");   // tile tt landed
        __builtin_amdgcn_s_barrier();
        __builtin_amdgcn_sched_barrier(0);
        GCOMPUTE(0);
        __builtin_amdgcn_s_barrier();
        // ---- sub-iter B: stage tile tt+2 -> buf0, compute buf1 ----
        if (tt + 2 < nt) {
            GSTAGE(tt + 2, 0);
            asm volatile("s_waitcnt vmcnt(4)" ::: "memory");
        } else {
            asm volatile("s_waitcnt vmcnt(0)" ::: "memory");
        }
        __builtin_amdgcn_s_barrier();
        __builtin_amdgcn_sched_barrier(0);
        GCOMPUTE(16384);
        __builtin_amdgcn_s_barrier();
    }
#undef GSTAGE
#undef GCOMPUTE

#pragma unroll
    for (int i = 0; i < 4; i++) {
        const int gr = m0 + wr + i * 16 + quad * 4;
#pragma unroll
        for (int j = 0; j < 2; j++) {
            const int gc = n0 + wc + j * 16 + l15;
            const float bv = bias[gc];
#pragma unroll
            for (int r = 0; r < 4; r++) {
                float v = acc[i][j][r] + bv;
                if (GELU) v = gelu_fast(v);
                if (RES)  v += res[(size_t)(gr + r) * N + gc];
                if (WF32) outF[(size_t)(gr + r) * N + gc] = v;
                if (WB16) outB[(size_t)(gr + r) * N + gc] = f2b(v);
            }
        }
    }
}

// ---------------------------------------------------------------------------
// Patch-embed MFMA GEMM: A gathered from bf16 image xb, W = conv_w bf16.
// Same 512-thread dbuf pipeline; A source is a per-lane gather. nt = 12.
// ---------------------------------------------------------------------------
__global__ __launch_bounds__(512) void patch_mfma_kernel(
    const unsigned short* __restrict__ xb, const unsigned short* __restrict__ W,
    const float* __restrict__ bias, float* __restrict__ outF)
{
    __shared__ unsigned short As[2 * 128 * 64];
    __shared__ unsigned short Ws[2 * 128 * 64];

    const int t    = threadIdx.x;
    const int m0   = blockIdx.x * 128;
    const int n0   = blockIdx.y * 128;
    const int wv   = t >> 6, lane = t & 63;
    const int wr   = (wv >> 2) * 64;
    const int wc   = (wv & 3) * 32;
    const int l15  = lane & 15, quad = lane >> 4;

    f32x4 acc[4][2];
#pragma unroll
    for (int i = 0; i < 4; i++)
#pragma unroll
        for (int j = 0; j < 2; j++)
#pragma unroll
            for (int r = 0; r < 4; r++) acc[i][j][r] = 0.0f;

    const int srow = wv * 8 + (lane >> 3);
    const int skk  = (((lane & 7) ^ ((lane >> 3) & 7)) * 8);  // swizzled k-chunk
    size_t xoff[2];
#pragma unroll
    for (int s = 0; s < 2; s++) {
        const int m  = m0 + s * 64 + srow;
        const int b  = m >> 10;
        const int idx = m & 1023;
        const int hh = idx >> 5, ww = idx & 31;
        xoff[s] = ((size_t)(b * 3) * 512 + (size_t)(hh * 16)) * 512 + ww * 16;
    }
    const unsigned short* gW = W + (size_t)(n0 + srow) * 768 + skk;
    char* lA = (char*)As + wv * 1024;
    char* lW = (char*)Ws + wv * 1024;

    const int cswz = (l15 & 7) * 8;

#define PSTAGE(tt, BUFOFF)                                                     \
    {                                                                          \
        const int kk = ((tt) << 6) + skk;   /* 8-aligned, within one px row */ \
        const int c  = kk >> 8;                                                \
        const int ph = (kk >> 4) & 15;                                         \
        const int pw = kk & 15;                                                \
        const size_t koff = (size_t)c * 262144 + (size_t)ph * 512 + pw;        \
        _Pragma("unroll")                                                      \
        for (int s = 0; s < 2; s++) {                                          \
            load_lds16(xb + xoff[s] + koff, lA + (BUFOFF) + s * 8192);         \
            load_lds16(gW + (size_t)(s * 64) * 768 + ((tt) << 6),              \
                       lW + (BUFOFF) + s * 8192);                              \
        }                                                                      \
    }

#define PCOMPUTE(BUFOFF)                                                       \
    {                                                                          \
        const unsigned short* Ab = (const unsigned short*)((const char*)As + (BUFOFF)); \
        const unsigned short* Wb = (const unsigned short*)((const char*)Ws + (BUFOFF)); \
        _Pragma("unroll")                                                      \
        for (int kh = 0; kh < 2; kh++) {                                       \
            const int coff = (kh * 32 + quad * 8) ^ cswz;                      \
            short8 af[4], wf[2];                                               \
            _Pragma("unroll")                                                  \
            for (int i = 0; i < 4; i++)                                        \
                af[i] = *(const short8*)&Ab[(wr + i * 16 + l15) * 64 + coff];  \
            _Pragma("unroll")                                                  \
            for (int j = 0; j < 2; j++)                                        \
                wf[j] = *(const short8*)&Wb[(wc + j * 16 + l15) * 64 + coff];  \
            _Pragma("unroll")                                                  \
            for (int i = 0; i < 4; i++)                                        \
                _Pragma("unroll")                                              \
                for (int j = 0; j < 2; j++)                                    \
                    acc[i][j] = __builtin_amdgcn_mfma_f32_16x16x32_bf16(       \
                        af[i], wf[j], acc[i][j], 0, 0, 0);                     \
        }                                                                      \
    }

    PSTAGE(0, 0);
    for (int tt = 0; tt < 12; tt += 2) {
        PSTAGE(tt + 1, 16384);
        asm volatile("s_waitcnt vmcnt(4)" ::: "memory");
        __builtin_amdgcn_s_barrier();
        __builtin_amdgcn_sched_barrier(0);
        PCOMPUTE(0);
        __builtin_amdgcn_s_barrier();
        if (tt + 2 < 12) {
            PSTAGE(tt + 2, 0);
            asm volatile("s_waitcnt vmcnt(4)" ::: "memory");
        } else {
            asm volatile("s_waitcnt vmcnt(0)" ::: "memory");
        }
        __builtin_amdgcn_s_barrier();
        __builtin_amdgcn_sched_barrier(0);
        PCOMPUTE(16384);
        __builtin_amdgcn_s_barrier();
    }
#undef PSTAGE
#undef PCOMPUTE

#pragma unroll
    for (int i = 0; i < 4; i++) {
        const int gr = m0 + wr + i * 16 + quad * 4;
#pragma unroll
        for (int j = 0; j < 2; j++) {
            const int gc = n0 + wc + j * 16 + l15;
            const float bv = bias[gc];
#pragma unroll
            for (int r = 0; r < 4; r++)
                outF[(size_t)(gr + r) * 256 + gc] = acc[i][j][r] + bv;
        }
    }
}

// ---------------------------------------------------------------------------
// LayerNorm + PE (table lookup). One block = one token (256 features).
// ---------------------------------------------------------------------------
__global__ __launch_bounds__(256) void ln_pe_kernel(
    const float* __restrict__ in, const float* __restrict__ w,
    const float* __restrict__ b, const float* __restrict__ pe_t,
    float* __restrict__ outF, unsigned short* __restrict__ outB)
{
    const int m = blockIdx.x;
    const int d = threadIdx.x;
    float v = in[(size_t)m * 256 + d];

    float s = v, s2 = v * v;
#pragma unroll
    for (int off = 32; off > 0; off >>= 1) {
        s  += __shfl_down(s,  off, 64);
        s2 += __shfl_down(s2, off, 64);
    }
    __shared__ float ss[4], ss2[4], stats[2];
    const int lane = d & 63, wid = d >> 6;
    if (lane == 0) { ss[wid] = s; ss2[wid] = s2; }
    __syncthreads();
    if (d == 0) {
        float a  = ss[0] + ss[1] + ss[2] + ss[3];
        float a2 = ss2[0] + ss2[1] + ss2[2] + ss2[3];
        float mean = a * (1.0f / 256.0f);
        float var  = a2 * (1.0f / 256.0f) - mean * mean;
        stats[0] = mean;
        stats[1] = rsqrtf(var + 1e-5f);
    }
    __syncthreads();
    const float mean = stats[0], rstd = stats[1];

    const int pos = m & 1023;
    float pe = pe_t[pos * 256 + d];

    float o = (v - mean) * rstd * w[d] + b[d] + pe;
    outF[(size_t)m * 256 + d] = o;
    outB[(size_t)m * 256 + d] = f2b(o);
}

// ---------------------------------------------------------------------------
// MFMA windowed attention. One block = one (batch, window, head).
// ---------------------------------------------------------------------------
__global__ __launch_bounds__(256) void attn_mfma_kernel(
    const unsigned short* __restrict__ qkv, unsigned short* __restrict__ out)
{
    __shared__ unsigned short Ps[64 * 72];   // P, stride 72 (b128-aligned, padded)
    __shared__ unsigned short Vt[32 * 72];   // V^T [headdim][key]

    const int blk = blockIdx.x;        // 0..4095
    const int h = blk & 7;
    const int w = (blk >> 3) & 15;
    const int b = blk >> 7;
    const int m_base = b * 1024 + w * 64;

    const int t = threadIdx.x;
    const int wv = t >> 6, lane = t & 63;
    const int l15 = lane & 15, quad = lane >> 4;

    // ---- stage V^T (cooperative, 8 elems/thread) ----
    {
        const int row = t >> 2;             // key 0..63
        const int c0  = (t & 3) * 8;        // headdim chunk
        const unsigned short* src = qkv + (size_t)(m_base + row) * 768 + 512 + h * 32 + c0;
        us8v v = *(const us8v*)src;
#pragma unroll
        for (int j = 0; j < 8; j++) Vt[(c0 + j) * 72 + row] = v[j];
    }

    // ---- QK^T: S strip (16x64) = 4 MFMAs ----
    short8 aq = *(const short8*)(qkv + (size_t)(m_base + wv * 16 + l15) * 768 + h * 32 + quad * 8);
    f32x4 c[4];
#pragma unroll
    for (int j = 0; j < 4; j++) {
        short8 bk = *(const short8*)(qkv + (size_t)(m_base + j * 16 + l15) * 768 + 256 + h * 32 + quad * 8);
        f32x4 z = {0.0f, 0.0f, 0.0f, 0.0f};
        c[j] = __builtin_amdgcn_mfma_f32_16x16x32_bf16(aq, bk, z, 0, 0, 0);
    }

    // ---- softmax over keys (row = quad*4+reg, col = j*16+l15) ----
    const float scale = 0.17677669529663687f; // 1/sqrt(32)
    float sm[4];
#pragma unroll
    for (int r = 0; r < 4; r++) {
        float m0 = -1e30f;
#pragma unroll
        for (int j = 0; j < 4; j++) { c[j][r] *= scale; m0 = fmaxf(m0, c[j][r]); }
#pragma unroll
        for (int d = 1; d < 16; d <<= 1) m0 = fmaxf(m0, __shfl_xor(m0, d, 64));
        float s0 = 0.0f;
#pragma unroll
        for (int j = 0; j < 4; j++) { float e = __expf(c[j][r] - m0); c[j][r] = e; s0 += e; }
#pragma unroll
        for (int d = 1; d < 16; d <<= 1) s0 += __shfl_xor(s0, d, 64);
        sm[r] = __builtin_amdgcn_rcpf(s0);
    }

    // ---- write P (bf16) to LDS ----
#pragma unroll
    for (int r = 0; r < 4; r++) {
        const int prow = wv * 16 + quad * 4 + r;
#pragma unroll
        for (int j = 0; j < 4; j++)
            Ps[prow * 72 + j * 16 + l15] = f2b(c[j][r] * sm[r]);
    }
    __syncthreads();

    // ---- PV: O strip (16x32) = 4 MFMAs ----
    short8 ap0 = *(const short8*)&Ps[(wv * 16 + l15) * 72 + quad * 8];
    short8 ap1 = *(const short8*)&Ps[(wv * 16 + l15) * 72 + 32 + quad * 8];
    f32x4 o[2];
#pragma unroll
    for (int nt = 0; nt < 2; nt++) {
        short8 bv0 = *(const short8*)&Vt[(nt * 16 + l15) * 72 + quad * 8];
        short8 bv1 = *(const short8*)&Vt[(nt * 16 + l15) * 72 + 32 + quad * 8];
        f32x4 z = {0.0f, 0.0f, 0.0f, 0.0f};
        o[nt] = __builtin_amdgcn_mfma_f32_16x16x32_bf16(ap0, bv0, z, 0, 0, 0);
        o[nt] = __builtin_amdgcn_mfma_f32_16x16x32_bf16(ap1, bv1, o[nt], 0, 0, 0);
    }

    // ---- write O (bf16) ----
#pragma unroll
    for (int nt = 0; nt < 2; nt++) {
#pragma unroll
        for (int r = 0; r < 4; r++) {
            const int row = m_base + wv * 16 + quad * 4 + r;
            out[(size_t)row * 256 + h * 32 + nt * 16 + l15] = f2b(o[nt][r]);
        }
    }
}

// ---------------------------------------------------------------------------
// Workspace layout (bytes), total ~186.5 MB (unchanged).
// ---------------------------------------------------------------------------
extern "C" void kernel_launch(void* const* d_in, const int* in_sizes, int n_in,
                              void* d_out, int out_size, void* d_ws, size_t ws_size,
                              hipStream_t stream)
{
    const float* x      = (const float*)d_in[0];
    const float* conv_w = (const float*)d_in[1];
    const float* conv_b = (const float*)d_in[2];
    const float* ln_w   = (const float*)d_in[3];
    const float* ln_b   = (const float*)d_in[4];
    const float* qkv_w  = (const float*)d_in[5];
    const float* qkv_b  = (const float*)d_in[6];
    const float* proj_w = (const float*)d_in[7];
    const float* proj_b = (const float*)d_in[8];
    const float* ff_w1  = (const float*)d_in[9];
    const float* ff_b1  = (const float*)d_in[10];
    const float* ff_w2  = (const float*)d_in[11];
    const float* ff_b2  = (const float*)d_in[12];
    float* out = (float*)d_out;

    char* ws = (char*)d_ws;
    unsigned short* xb    = (unsigned short*)(ws);                 // SLOT_A
    unsigned short* hidb  = (unsigned short*)(ws);                 // SLOT_A reuse
    float*          h0    = (float*)(ws + 67108864);               // SLOT_B
    unsigned short* qkvb  = (unsigned short*)(ws + 67108864);      // SLOT_B reuse
    float*          pe_t  = (float*)(ws + 100663296);              // SLOT_B tail
    float*          h1f   = (float*)(ws + 117440512);
    unsigned short* h1b   = (unsigned short*)(ws + 150994944);     // SLOT_C
    unsigned short* aob   = (unsigned short*)(ws + 150994944);     // SLOT_C reuse
    unsigned short* f1b   = (unsigned short*)(ws + 167772160);     // SLOT_D
    unsigned short* h2b   = (unsigned short*)(ws + 167772160);     // SLOT_D reuse
    unsigned short* wbase = (unsigned short*)(ws + 184549376);
    unsigned short* conv_wb = wbase;                 // 196608
    unsigned short* qkv_wb  = wbase + 196608;        // 196608
    unsigned short* proj_wb = wbase + 393216;        // 65536
    unsigned short* ff_w1b  = wbase + 458752;        // 262144
    unsigned short* ff_w2b  = wbase + 720896;        // 262144

    const int M = M_TOK;
    dim3 blk(256);
    dim3 blk512(512);

    // K0: conversions + PE table
    cvt_f2b_kernel<<<dim3(25165824 / 1024), blk, 0, stream>>>(x, xb, 25165824);
    cvt_weights_kernel<<<dim3(960), blk, 0, stream>>>(
        conv_w, qkv_w, proj_w, ff_w1, ff_w2,
        conv_wb, qkv_wb, proj_wb, ff_w1b, ff_w2b);
    pe_init_kernel<<<dim3(1024), blk, 0, stream>>>(pe_t);

    // K1: patch embed -> h0 (fp32)
    patch_mfma_kernel<<<dim3(M / 128, 2), blk512, 0, stream>>>(xb, conv_wb, conv_b, h0);
    // K2: LN + PE -> h1f (fp32 residual) + h1b (bf16)
    ln_pe_kernel<<<dim3(M), blk, 0, stream>>>(h0, ln_w, ln_b, pe_t, h1f, h1b);
    // K3: FFN1a: gelu(h1 @ w1^T + b1) -> hidb (bf16)
    mfma_gemm_kernel<true, false, false, true><<<dim3(M / 128, 8), blk512, 0, stream>>>(
        h1b, ff_w1b, ff_b1, nullptr, nullptr, hidb, M, 1024, 256);
    // K4: FFN1b: hidb @ w2^T + b2 -> f1b (bf16)
    mfma_gemm_kernel<false, false, false, true><<<dim3(M / 128, 2), blk512, 0, stream>>>(
        hidb, ff_w2b, ff_b2, nullptr, nullptr, f1b, M, 256, 1024);
    // K5: qkv: f1b @ qkv_w^T + qkv_b -> qkvb (bf16)
    mfma_gemm_kernel<false, false, false, true><<<dim3(M / 128, 6), blk512, 0, stream>>>(
        f1b, qkv_wb, qkv_b, nullptr, nullptr, qkvb, M, 768, 256);
    // K6: windowed attention (MFMA): qkvb -> aob (bf16)
    attn_mfma_kernel<<<dim3(4096), blk, 0, stream>>>(qkvb, aob);
    // K7: proj + residual(h1f): aob @ proj_w^T + proj_b + h1f -> out + h2b
    mfma_gemm_kernel<false, true, true, true><<<dim3(M / 128, 2), blk512, 0, stream>>>(
        aob, proj_wb, proj_b, h1f, out, h2b, M, 256, 256);
    // K8: FFN2a: gelu(h2b @ w1^T + b1) -> hidb (bf16)
    mfma_gemm_kernel<true, false, false, true><<<dim3(M / 128, 8), blk512, 0, stream>>>(
        h2b, ff_w1b, ff_b1, nullptr, nullptr, hidb, M, 1024, 256);
    // K9: FFN2b + final residual: hidb @ w2^T + b2 + out -> out
    mfma_gemm_kernel<false, true, true, false><<<dim3(M / 128, 2), blk512, 0, stream>>>(
        hidb, ff_w2b, ff_b2, out, out, nullptr, M, 256, 1024);
}

// Round 9
// 388.958 us; speedup vs baseline: 1.5940x; 1.0137x over previous
//
#include <hip/hip_runtime.h>
#include <math.h>

// ============================================================================
// ViT block on MI355X — Round 11:
//   * Base = round 10 (best, 394 µs): 512-thr GEMMs, BK=64 dbuf, counted
//     vmcnt, 2 barriers/tile. GEMMs/attention/LN unchanged.
//   * Change: cvt_f2b (150 MB pass, ~24 µs) ELIMINATED — its only consumer
//     was patch A. New fused patch kernel: N-tile=256 (ygrid 1, 256 blocks
//     = 1/CU), A reg-staged from fp32 image with inline f2b (bit-identical
//     to the old cvt) + swizzled ds_write; W via global_load_lds (4 rounds).
//     One barrier per K-tile; A/W latency hides under compute.
// ============================================================================

#define M_TOK 32768

typedef __attribute__((ext_vector_type(8))) short  short8;   // 8 bf16 (4 VGPRs)
typedef __attribute__((ext_vector_type(4))) float  f32x4;
typedef __attribute__((ext_vector_type(8))) unsigned short us8v;
typedef __attribute__((ext_vector_type(4))) unsigned short us4v;

__device__ __forceinline__ unsigned short f2b(float f) {
    union { float f; unsigned u; } c; c.f = f;
    unsigned r = c.u + 0x7fffu + ((c.u >> 16) & 1u);   // RNE
    return (unsigned short)(r >> 16);
}
__device__ __forceinline__ float gelu_fast(float x) {
    // 0.5x(1+tanh(c0(x+0.044715x^3))) == x * sigmoid(2*c0*(x+0.044715x^3))
    const float c0 = 0.7978845608028654f;            // sqrt(2/pi)
    const float c1 = 0.044715f * 0.7978845608028654f;
    float z = x * (c0 + c1 * x * x);
    float e = __expf(-2.0f * z);
    return x * __builtin_amdgcn_rcpf(1.0f + e);
}
// async global->LDS, 16B per lane; lds dest must be wave-uniform base (+lane*16 by HW)
__device__ __forceinline__ void load_lds16(const unsigned short* g, void* lds) {
    __builtin_amdgcn_global_load_lds(
        (const __attribute__((address_space(1))) unsigned int*)g,
        (__attribute__((address_space(3))) unsigned int*)lds, 16, 0, 0);
}

// ---------------------------------------------------------------------------
// All 5 weight tensors converted in ONE launch (ranges in 1024-elem blocks)
// ---------------------------------------------------------------------------
__global__ __launch_bounds__(256) void cvt_weights_kernel(
    const float* __restrict__ s0, const float* __restrict__ s1,
    const float* __restrict__ s2, const float* __restrict__ s3,
    const float* __restrict__ s4,
    unsigned short* __restrict__ d0, unsigned short* __restrict__ d1,
    unsigned short* __restrict__ d2, unsigned short* __restrict__ d3,
    unsigned short* __restrict__ d4)
{
    const int bid = blockIdx.x;
    const float* src; unsigned short* dst; int off;
    if      (bid < 192) { src = s0; dst = d0; off = bid; }
    else if (bid < 384) { src = s1; dst = d1; off = bid - 192; }
    else if (bid < 448) { src = s2; dst = d2; off = bid - 384; }
    else if (bid < 704) { src = s3; dst = d3; off = bid - 448; }
    else                { src = s4; dst = d4; off = bid - 704; }
    const int i = off * 1024 + threadIdx.x * 4;
    float4 v = *(const float4*)(src + i);
    us4v o;
    o[0] = f2b(v.x); o[1] = f2b(v.y); o[2] = f2b(v.z); o[3] = f2b(v.w);
    *(us4v*)(dst + i) = o;
}

// ---------------------------------------------------------------------------
// Sinusoidal PE table: pe[pos][d], pos<1024, d<256.
// ---------------------------------------------------------------------------
__global__ __launch_bounds__(256) void pe_init_kernel(float* __restrict__ pe)
{
    const int pos = blockIdx.x;
    const int d   = threadIdx.x;
    const int ieven = d & ~1;
    float div = expf(-9.210340371976184f * (float)ieven * (1.0f / 256.0f));
    float ang = (float)pos * div;
    pe[pos * 256 + d] = (d & 1) ? cosf(ang) : sinf(ang);
}

// ---------------------------------------------------------------------------
// MFMA GEMM: C = A (MxK) . W^T (NxK) + bias (+gelu/res)
// 128x128 tile, BK=64, 512 thr = 8 waves (2Mx4N, 64x32 per wave), dbuf LDS.
// XOR swizzle: stored chunk c of row holds data chunk c ^ (row&7).
// (unchanged from round 10)
// ---------------------------------------------------------------------------
template<bool GELU, bool RES, bool WF32, bool WB16>
__global__ __launch_bounds__(512) void mfma_gemm_kernel(
    const unsigned short* __restrict__ A, const unsigned short* __restrict__ W,
    const float* __restrict__ bias, const float* __restrict__ res,
    float* __restrict__ outF, unsigned short* __restrict__ outB,
    int M, int N, int K)
{
    __shared__ unsigned short As[2 * 128 * 64];
    __shared__ unsigned short Ws[2 * 128 * 64];

    const int t    = threadIdx.x;
    const int m0   = blockIdx.x * 128;
    const int n0   = blockIdx.y * 128;
    const int wv   = t >> 6, lane = t & 63;
    const int wr   = (wv >> 2) * 64;       // M-group: 0 or 64
    const int wc   = (wv & 3) * 32;        // N-group: 0,32,64,96
    const int l15  = lane & 15, quad = lane >> 4;

    f32x4 acc[4][2];
#pragma unroll
    for (int i = 0; i < 4; i++)
#pragma unroll
        for (int j = 0; j < 2; j++)
#pragma unroll
            for (int r = 0; r < 4; r++) acc[i][j][r] = 0.0f;

    const int srow = wv * 8 + (lane >> 3);
    const int skk  = (((lane & 7) ^ ((lane >> 3) & 7)) * 8);
    const unsigned short* gA = A + (size_t)(m0 + srow) * K + skk;
    const unsigned short* gW = W + (size_t)(n0 + srow) * K + skk;
    char* lA = (char*)As + wv * 1024;      // + buf*16384 + s*8192
    char* lW = (char*)Ws + wv * 1024;

    const int cswz = (l15 & 7) * 8;        // read-side XOR (shorts)
    const int nt   = K >> 6;               // 4 or 16 (always even)

#define GSTAGE(tt, BUFOFF)                                                     \
    {                                                                          \
        const int kk = (tt) << 6;                                              \
        _Pragma("unroll")                                                      \
        for (int s = 0; s < 2; s++) {                                          \
            load_lds16(gA + (size_t)(s * 64) * K + kk, lA + (BUFOFF) + s * 8192); \
            load_lds16(gW + (size_t)(s * 64) * K + kk, lW + (BUFOFF) + s * 8192); \
        }                                                                      \
    }

#define GCOMPUTE(BUFOFF)                                                       \
    {                                                                          \
        const unsigned short* Ab = (const unsigned short*)((const char*)As + (BUFOFF)); \
        const unsigned short* Wb = (const unsigned short*)((const char*)Ws + (BUFOFF)); \
        _Pragma("unroll")                                                      \
        for (int kh = 0; kh < 2; kh++) {                                       \
            const int coff = (kh * 32 + quad * 8) ^ cswz;                      \
            short8 af[4], wf[2];                                               \
            _Pragma("unroll")                                                  \
            for (int i = 0; i < 4; i++)                                        \
                af[i] = *(const short8*)&Ab[(wr + i * 16 + l15) * 64 + coff];  \
            _Pragma("unroll")                                                  \
            for (int j = 0; j < 2; j++)                                        \
                wf[j] = *(const short8*)&Wb[(wc + j * 16 + l15) * 64 + coff];  \
            _Pragma("unroll")                                                  \
            for (int i = 0; i < 4; i++)                                        \
                _Pragma("unroll")                                              \
                for (int j = 0; j < 2; j++)                                    \
                    acc[i][j] = __builtin_amdgcn_mfma_f32_16x16x32_bf16(       \
                        af[i], wf[j], acc[i][j], 0, 0, 0);                     \
        }                                                                      \
    }

    GSTAGE(0, 0);                               // prologue: tile 0 -> buf0
    for (int tt = 0; tt < nt; tt += 2) {
        // ---- sub-iter A: stage tile tt+1 -> buf1, compute buf0 ----
        GSTAGE(tt + 1, 16384);
        asm volatile("s_waitcnt vmcnt(4)" ::: "memory");   // tile tt landed
        __builtin_amdgcn_s_barrier();
        __builtin_amdgcn_sched_barrier(0);
        GCOMPUTE(0);
        __builtin_amdgcn_s_barrier();
        // ---- sub-iter B: stage tile tt+2 -> buf0, compute buf1 ----
        if (tt + 2 < nt) {
            GSTAGE(tt + 2, 0);
            asm volatile("s_waitcnt vmcnt(4)" ::: "memory");
        } else {
            asm volatile("s_waitcnt vmcnt(0)" ::: "memory");
        }
        __builtin_amdgcn_s_barrier();
        __builtin_amdgcn_sched_barrier(0);
        GCOMPUTE(16384);
        __builtin_amdgcn_s_barrier();
    }
#undef GSTAGE
#undef GCOMPUTE

#pragma unroll
    for (int i = 0; i < 4; i++) {
        const int gr = m0 + wr + i * 16 + quad * 4;
#pragma unroll
        for (int j = 0; j < 2; j++) {
            const int gc = n0 + wc + j * 16 + l15;
            const float bv = bias[gc];
#pragma unroll
            for (int r = 0; r < 4; r++) {
                float v = acc[i][j][r] + bv;
                if (GELU) v = gelu_fast(v);
                if (RES)  v += res[(size_t)(gr + r) * N + gc];
                if (WF32) outF[(size_t)(gr + r) * N + gc] = v;
                if (WB16) outB[(size_t)(gr + r) * N + gc] = f2b(v);
            }
        }
    }
}

// ---------------------------------------------------------------------------
// FUSED patch-embed GEMM: reads fp32 image x directly, converts to bf16
// in-register (same f2b as the old cvt pass -> bit-identical), swizzled
// ds_write for A; W (conv_wb, [256x768] bf16) via global_load_lds.
// N-tile = 256 (full), M-tile = 128 -> grid 256 blocks (1/CU), 512 thr,
// 8 waves 2Mx4N (64x64 out per wave). BK=64, nt=12, dbuf, 1 barrier/tile:
//   { issue A-regs(t+1)+W-lds(t+1)->nxt; compute(t); vmcnt(0);
//     cvt+ds_write A(t+1)->nxt; lgkmcnt(0); barrier }
// LDS: A 2x16KB + W 2x32KB = 96 KB.
// ---------------------------------------------------------------------------
__global__ __launch_bounds__(512) void patch_fused_kernel(
    const float* __restrict__ x, const unsigned short* __restrict__ W,
    const float* __restrict__ bias, float* __restrict__ outF)
{
    __shared__ unsigned short As[2 * 128 * 64];   // 2 x 16 KB
    __shared__ unsigned short Ws[2 * 256 * 64];   // 2 x 32 KB

    const int t    = threadIdx.x;
    const int m0   = blockIdx.x * 128;
    const int wv   = t >> 6, lane = t & 63;
    const int wr   = (wv >> 2) * 64;       // M-group: 0 or 64
    const int wc   = (wv & 3) * 64;        // N-group: 0,64,128,192
    const int l15  = lane & 15, quad = lane >> 4;

    f32x4 acc[4][4];
#pragma unroll
    for (int i = 0; i < 4; i++)
#pragma unroll
        for (int j = 0; j < 4; j++)
#pragma unroll
            for (int r = 0; r < 4; r++) acc[i][j][r] = 0.0f;

    // ---- A staging map (reg-staged): thread owns row ar, 16 elems at ac0
    const int ar  = t >> 2;                // 0..127
    const int ac0 = (t & 3) * 16;          // 0,16,32,48
    const int am  = m0 + ar;
    const int ab  = am >> 10;
    const int ahh = (am >> 5) & 31;
    const int aww = am & 31;
    const float* axbase = x + (size_t)ab * 786432 + (size_t)ahh * 8192 + aww * 16;
    const int alc = ac0 >> 3;              // logical chunk (0,2,4,6)
    char* aw0 = (char*)As + ar * 128 + ((alc    ) ^ (ar & 7)) * 16;
    char* aw1 = (char*)As + ar * 128 + ((alc + 1) ^ (ar & 7)) * 16;

    // ---- W staging map (global_load_lds, pre-swizzled source, 4 rounds)
    const int wsrow = wv * 8 + (lane >> 3);
    const int wskk  = (((lane & 7) ^ ((lane >> 3) & 7)) * 8);
    const unsigned short* gW = W + (size_t)wsrow * 768 + wskk;
    char* lW = (char*)Ws + wv * 1024;      // + BUFOFF + s*8192

    const int cswz = (l15 & 7) * 8;

    float4 av0, av1, av2, av3;

#define PA_ISSUE(tt)                                                           \
    {                                                                          \
        const int k0 = ((tt) << 6) + ac0;                                      \
        const int c  = k0 >> 8;                                                \
        const int ph = (k0 >> 4) & 15;                                         \
        const float* s = axbase + (size_t)c * 262144 + ph * 512;               \
        av0 = *(const float4*)(s);                                             \
        av1 = *(const float4*)(s + 4);                                         \
        av2 = *(const float4*)(s + 8);                                         \
        av3 = *(const float4*)(s + 12);                                        \
    }
#define PA_WRITE(BUFOFF)                                                       \
    {                                                                          \
        us8v o0, o1;                                                           \
        o0[0] = f2b(av0.x); o0[1] = f2b(av0.y); o0[2] = f2b(av0.z); o0[3] = f2b(av0.w); \
        o0[4] = f2b(av1.x); o0[5] = f2b(av1.y); o0[6] = f2b(av1.z); o0[7] = f2b(av1.w); \
        o1[0] = f2b(av2.x); o1[1] = f2b(av2.y); o1[2] = f2b(av2.z); o1[3] = f2b(av2.w); \
        o1[4] = f2b(av3.x); o1[5] = f2b(av3.y); o1[6] = f2b(av3.z); o1[7] = f2b(av3.w); \
        *(us8v*)(aw0 + (BUFOFF)) = o0;                                         \
        *(us8v*)(aw1 + (BUFOFF)) = o1;                                         \
    }
#define PW_ISSUE(tt, BUFOFF)                                                   \
    {                                                                          \
        const int kk = (tt) << 6;                                              \
        _Pragma("unroll")                                                      \
        for (int s = 0; s < 4; s++)                                            \
            load_lds16(gW + (size_t)(s * 64) * 768 + kk, lW + (BUFOFF) + s * 8192); \
    }
#define PCOMPUTE(AOFF, WOFF)                                                   \
    {                                                                          \
        const unsigned short* Ab = (const unsigned short*)((const char*)As + (AOFF)); \
        const unsigned short* Wb = (const unsigned short*)((const char*)Ws + (WOFF)); \
        _Pragma("unroll")                                                      \
        for (int kh = 0; kh < 2; kh++) {                                       \
            const int coff = (kh * 32 + quad * 8) ^ cswz;                      \
            short8 af[4], wf[4];                                               \
            _Pragma("unroll")                                                  \
            for (int i = 0; i < 4; i++)                                        \
                af[i] = *(const short8*)&Ab[(wr + i * 16 + l15) * 64 + coff];  \
            _Pragma("unroll")                                                  \
            for (int j = 0; j < 4; j++)                                        \
                wf[j] = *(const short8*)&Wb[(wc + j * 16 + l15) * 64 + coff];  \
            _Pragma("unroll")                                                  \
            for (int i = 0; i < 4; i++)                                        \
                _Pragma("unroll")                                              \
                for (int j = 0; j < 4; j++)                                    \
                    acc[i][j] = __builtin_amdgcn_mfma_f32_16x16x32_bf16(       \
                        af[i], wf[j], acc[i][j], 0, 0, 0);                     \
        }                                                                      \
    }

    // prologue: tile 0 -> buf0
    PA_ISSUE(0);
    PW_ISSUE(0, 0);
    asm volatile("s_waitcnt vmcnt(0)" ::: "memory");
    PA_WRITE(0);
    asm volatile("s_waitcnt lgkmcnt(0)" ::: "memory");
    __builtin_amdgcn_s_barrier();
    __builtin_amdgcn_sched_barrier(0);

    for (int tt = 0; tt < 12; ++tt) {
        const int aoff_c = (tt & 1) * 16384;
        const int woff_c = (tt & 1) * 32768;
        if (tt < 11) {
            PA_ISSUE(tt + 1);
            PW_ISSUE(tt + 1, woff_c ^ 32768);
        }
        PCOMPUTE(aoff_c, woff_c);
        if (tt < 11) {
            asm volatile("s_waitcnt vmcnt(0)" ::: "memory");
            PA_WRITE(aoff_c ^ 16384);
            asm volatile("s_waitcnt lgkmcnt(0)" ::: "memory");
            __builtin_amdgcn_s_barrier();
            __builtin_amdgcn_sched_barrier(0);
        }
    }
#undef PA_ISSUE
#undef PA_WRITE
#undef PW_ISSUE
#undef PCOMPUTE

#pragma unroll
    for (int i = 0; i < 4; i++) {
        const int gr = m0 + wr + i * 16 + quad * 4;
#pragma unroll
        for (int j = 0; j < 4; j++) {
            const int gc = wc + j * 16 + l15;
            const float bv = bias[gc];
#pragma unroll
            for (int r = 0; r < 4; r++)
                outF[(size_t)(gr + r) * 256 + gc] = acc[i][j][r] + bv;
        }
    }
}

// ---------------------------------------------------------------------------
// LayerNorm + PE (table lookup). One block = one token (256 features).
// ---------------------------------------------------------------------------
__global__ __launch_bounds__(256) void ln_pe_kernel(
    const float* __restrict__ in, const float* __restrict__ w,
    const float* __restrict__ b, const float* __restrict__ pe_t,
    float* __restrict__ outF, unsigned short* __restrict__ outB)
{
    const int m = blockIdx.x;
    const int d = threadIdx.x;
    float v = in[(size_t)m * 256 + d];

    float s = v, s2 = v * v;
#pragma unroll
    for (int off = 32; off > 0; off >>= 1) {
        s  += __shfl_down(s,  off, 64);
        s2 += __shfl_down(s2, off, 64);
    }
    __shared__ float ss[4], ss2[4], stats[2];
    const int lane = d & 63, wid = d >> 6;
    if (lane == 0) { ss[wid] = s; ss2[wid] = s2; }
    __syncthreads();
    if (d == 0) {
        float a  = ss[0] + ss[1] + ss[2] + ss[3];
        float a2 = ss2[0] + ss2[1] + ss2[2] + ss2[3];
        float mean = a * (1.0f / 256.0f);
        float var  = a2 * (1.0f / 256.0f) - mean * mean;
        stats[0] = mean;
        stats[1] = rsqrtf(var + 1e-5f);
    }
    __syncthreads();
    const float mean = stats[0], rstd = stats[1];

    const int pos = m & 1023;
    float pe = pe_t[pos * 256 + d];

    float o = (v - mean) * rstd * w[d] + b[d] + pe;
    outF[(size_t)m * 256 + d] = o;
    outB[(size_t)m * 256 + d] = f2b(o);
}

// ---------------------------------------------------------------------------
// MFMA windowed attention. One block = one (batch, window, head).
// ---------------------------------------------------------------------------
__global__ __launch_bounds__(256) void attn_mfma_kernel(
    const unsigned short* __restrict__ qkv, unsigned short* __restrict__ out)
{
    __shared__ unsigned short Ps[64 * 72];   // P, stride 72 (b128-aligned, padded)
    __shared__ unsigned short Vt[32 * 72];   // V^T [headdim][key]

    const int blk = blockIdx.x;        // 0..4095
    const int h = blk & 7;
    const int w = (blk >> 3) & 15;
    const int b = blk >> 7;
    const int m_base = b * 1024 + w * 64;

    const int t = threadIdx.x;
    const int wv = t >> 6, lane = t & 63;
    const int l15 = lane & 15, quad = lane >> 4;

    // ---- stage V^T (cooperative, 8 elems/thread) ----
    {
        const int row = t >> 2;             // key 0..63
        const int c0  = (t & 3) * 8;        // headdim chunk
        const unsigned short* src = qkv + (size_t)(m_base + row) * 768 + 512 + h * 32 + c0;
        us8v v = *(const us8v*)src;
#pragma unroll
        for (int j = 0; j < 8; j++) Vt[(c0 + j) * 72 + row] = v[j];
    }

    // ---- QK^T: S strip (16x64) = 4 MFMAs ----
    short8 aq = *(const short8*)(qkv + (size_t)(m_base + wv * 16 + l15) * 768 + h * 32 + quad * 8);
    f32x4 c[4];
#pragma unroll
    for (int j = 0; j < 4; j++) {
        short8 bk = *(const short8*)(qkv + (size_t)(m_base + j * 16 + l15) * 768 + 256 + h * 32 + quad * 8);
        f32x4 z = {0.0f, 0.0f, 0.0f, 0.0f};
        c[j] = __builtin_amdgcn_mfma_f32_16x16x32_bf16(aq, bk, z, 0, 0, 0);
    }

    // ---- softmax over keys (row = quad*4+reg, col = j*16+l15) ----
    const float scale = 0.17677669529663687f; // 1/sqrt(32)
    float sm[4];
#pragma unroll
    for (int r = 0; r < 4; r++) {
        float m0 = -1e30f;
#pragma unroll
        for (int j = 0; j < 4; j++) { c[j][r] *= scale; m0 = fmaxf(m0, c[j][r]); }
#pragma unroll
        for (int d = 1; d < 16; d <<= 1) m0 = fmaxf(m0, __shfl_xor(m0, d, 64));
        float s0 = 0.0f;
#pragma unroll
        for (int j = 0; j < 4; j++) { float e = __expf(c[j][r] - m0); c[j][r] = e; s0 += e; }
#pragma unroll
        for (int d = 1; d < 16; d <<= 1) s0 += __shfl_xor(s0, d, 64);
        sm[r] = __builtin_amdgcn_rcpf(s0);
    }

    // ---- write P (bf16) to LDS ----
#pragma unroll
    for (int r = 0; r < 4; r++) {
        const int prow = wv * 16 + quad * 4 + r;
#pragma unroll
        for (int j = 0; j < 4; j++)
            Ps[prow * 72 + j * 16 + l15] = f2b(c[j][r] * sm[r]);
    }
    __syncthreads();

    // ---- PV: O strip (16x32) = 4 MFMAs ----
    short8 ap0 = *(const short8*)&Ps[(wv * 16 + l15) * 72 + quad * 8];
    short8 ap1 = *(const short8*)&Ps[(wv * 16 + l15) * 72 + 32 + quad * 8];
    f32x4 o[2];
#pragma unroll
    for (int nt = 0; nt < 2; nt++) {
        short8 bv0 = *(const short8*)&Vt[(nt * 16 + l15) * 72 + quad * 8];
        short8 bv1 = *(const short8*)&Vt[(nt * 16 + l15) * 72 + 32 + quad * 8];
        f32x4 z = {0.0f, 0.0f, 0.0f, 0.0f};
        o[nt] = __builtin_amdgcn_mfma_f32_16x16x32_bf16(ap0, bv0, z, 0, 0, 0);
        o[nt] = __builtin_amdgcn_mfma_f32_16x16x32_bf16(ap1, bv1, o[nt], 0, 0, 0);
    }

    // ---- write O (bf16) ----
#pragma unroll
    for (int nt = 0; nt < 2; nt++) {
#pragma unroll
        for (int r = 0; r < 4; r++) {
            const int row = m_base + wv * 16 + quad * 4 + r;
            out[(size_t)row * 256 + h * 32 + nt * 16 + l15] = f2b(o[nt][r]);
        }
    }
}

// ---------------------------------------------------------------------------
// Workspace layout (bytes), total ~186.5 MB. xb slot no longer used for the
// image (patch reads x directly); SLOT_A is hidb only.
// ---------------------------------------------------------------------------
extern "C" void kernel_launch(void* const* d_in, const int* in_sizes, int n_in,
                              void* d_out, int out_size, void* d_ws, size_t ws_size,
                              hipStream_t stream)
{
    const float* x      = (const float*)d_in[0];
    const float* conv_w = (const float*)d_in[1];
    const float* conv_b = (const float*)d_in[2];
    const float* ln_w   = (const float*)d_in[3];
    const float* ln_b   = (const float*)d_in[4];
    const float* qkv_w  = (const float*)d_in[5];
    const float* qkv_b  = (const float*)d_in[6];
    const float* proj_w = (const float*)d_in[7];
    const float* proj_b = (const float*)d_in[8];
    const float* ff_w1  = (const float*)d_in[9];
    const float* ff_b1  = (const float*)d_in[10];
    const float* ff_w2  = (const float*)d_in[11];
    const float* ff_b2  = (const float*)d_in[12];
    float* out = (float*)d_out;

    char* ws = (char*)d_ws;
    unsigned short* hidb  = (unsigned short*)(ws);                 // SLOT_A
    float*          h0    = (float*)(ws + 67108864);               // SLOT_B
    unsigned short* qkvb  = (unsigned short*)(ws + 67108864);      // SLOT_B reuse
    float*          pe_t  = (float*)(ws + 100663296);              // SLOT_B tail
    float*          h1f   = (float*)(ws + 117440512);
    unsigned short* h1b   = (unsigned short*)(ws + 150994944);     // SLOT_C
    unsigned short* aob   = (unsigned short*)(ws + 150994944);     // SLOT_C reuse
    unsigned short* f1b   = (unsigned short*)(ws + 167772160);     // SLOT_D
    unsigned short* h2b   = (unsigned short*)(ws + 167772160);     // SLOT_D reuse
    unsigned short* wbase = (unsigned short*)(ws + 184549376);
    unsigned short* conv_wb = wbase;                 // 196608
    unsigned short* qkv_wb  = wbase + 196608;        // 196608
    unsigned short* proj_wb = wbase + 393216;        // 65536
    unsigned short* ff_w1b  = wbase + 458752;        // 262144
    unsigned short* ff_w2b  = wbase + 720896;        // 262144

    const int M = M_TOK;
    dim3 blk(256);
    dim3 blk512(512);

    // K0: weight conversions + PE table (image conversion fused into patch)
    cvt_weights_kernel<<<dim3(960), blk, 0, stream>>>(
        conv_w, qkv_w, proj_w, ff_w1, ff_w2,
        conv_wb, qkv_wb, proj_wb, ff_w1b, ff_w2b);
    pe_init_kernel<<<dim3(1024), blk, 0, stream>>>(pe_t);

    // K1: fused patch embed (fp32 image -> bf16 in-kernel) -> h0 (fp32)
    patch_fused_kernel<<<dim3(M / 128), blk512, 0, stream>>>(x, conv_wb, conv_b, h0);
    // K2: LN + PE -> h1f (fp32 residual) + h1b (bf16)
    ln_pe_kernel<<<dim3(M), blk, 0, stream>>>(h0, ln_w, ln_b, pe_t, h1f, h1b);
    // K3: FFN1a: gelu(h1 @ w1^T + b1) -> hidb (bf16)
    mfma_gemm_kernel<true, false, false, true><<<dim3(M / 128, 8), blk512, 0, stream>>>(
        h1b, ff_w1b, ff_b1, nullptr, nullptr, hidb, M, 1024, 256);
    // K4: FFN1b: hidb @ w2^T + b2 -> f1b (bf16)
    mfma_gemm_kernel<false, false, false, true><<<dim3(M / 128, 2), blk512, 0, stream>>>(
        hidb, ff_w2b, ff_b2, nullptr, nullptr, f1b, M, 256, 1024);
    // K5: qkv: f1b @ qkv_w^T + qkv_b -> qkvb (bf16)
    mfma_gemm_kernel<false, false, false, true><<<dim3(M / 128, 6), blk512, 0, stream>>>(
        f1b, qkv_wb, qkv_b, nullptr, nullptr, qkvb, M, 768, 256);
    // K6: windowed attention (MFMA): qkvb -> aob (bf16)
    attn_mfma_kernel<<<dim3(4096), blk, 0, stream>>>(qkvb, aob);
    // K7: proj + residual(h1f): aob @ proj_w^T + proj_b + h1f -> out + h2b
    mfma_gemm_kernel<false, true, true, true><<<dim3(M / 128, 2), blk512, 0, stream>>>(
        aob, proj_wb, proj_b, h1f, out, h2b, M, 256, 256);
    // K8: FFN2a: gelu(h2b @ w1^T + b1) -> hidb (bf16)
    mfma_gemm_kernel<true, false, false, true><<<dim3(M / 128, 8), blk512, 0, stream>>>(
        h2b, ff_w1b, ff_b1, nullptr, nullptr, hidb, M, 1024, 256);
    // K9: FFN2b + final residual: hidb @ w2^T + b2 + out -> out
    mfma_gemm_kernel<false, true, true, false><<<dim3(M / 128, 2), blk512, 0, stream>>>(
        hidb, ff_w2b, ff_b2, out, out, nullptr, M, 256, 1024);
}